// Round 12
// baseline (278.464 us; speedup 1.0000x reference)
//
#include <hip/hip_runtime.h>

#define N_NODES 100000
#define N_EDGES 800000
#define DF 64
#define NGRAPH 512
#define LDIM 192   // L * D
#define BN_EPS 1e-5
#define NTILES 6250      // N_NODES / 16
#define GIN_GRID 782     // ceil(NTILES / 8 waves)
#define NWT (GIN_GRID * 8)   // partial-stat slots (one per wave/tile)
#define COLS_CAP 2600000     // sum of padded degrees < 2.4M
#define NBUCK 782            // ceil(N_NODES / 128)
#define BCAP 2048            // max edges per bucket (avg 1023)
#define NBLK 128             // counting-sort blocks
#define CHUNK 6250           // N_EDGES / NBLK

typedef __attribute__((ext_vector_type(8))) short bf16x8;
typedef __attribute__((ext_vector_type(4))) float f32x4;

__device__ inline short f2bf(float x) {
    union { float f; unsigned u; } v; v.f = x;
    unsigned r = v.u + 0x7fff + ((v.u >> 16) & 1);   // RNE
    return (short)(r >> 16);
}

__device__ inline float bf2f(unsigned short u) {
    union { unsigned u; float f; } v;
    v.u = ((unsigned)u) << 16;
    return v.f;
}

__device__ inline int pdeg_of(int d) {   // pad to multiple of 16, min 16
    int p = (d + 15) & ~15;
    return p < 16 ? 16 : p;
}

// ---------------------------------------------------------------------------
// Counting-sort CSR build (no global atomics). bucket = row >> 7.
// ---------------------------------------------------------------------------
__global__ __launch_bounds__(256) void blk_hist_kernel(
    const int* __restrict__ ei, int* __restrict__ hist)
{
    __shared__ int hh[NBUCK];
    int blk = blockIdx.x, tid = threadIdx.x;
    for (int i = tid; i < NBUCK; i += 256) hh[i] = 0;
    __syncthreads();
    int start = blk * CHUNK, end = min(start + CHUNK, N_EDGES);
    for (int e = start + tid; e < end; e += 256)
        atomicAdd(&hh[ei[e] >> 7], 1);
    __syncthreads();
    for (int i = tid; i < NBUCK; i += 256) hist[blk * NBUCK + i] = hh[i];
}

__global__ __launch_bounds__(NBLK) void blk_scan_kernel(
    const int* __restrict__ hist, int* __restrict__ pos, int* __restrict__ cnt)
{
    __shared__ int buf[NBLK];
    int k = blockIdx.x, b = threadIdx.x;
    int v = hist[b * NBUCK + k];
    buf[b] = v;
    __syncthreads();
    for (int o = 1; o < NBLK; o <<= 1) {
        int t = (b >= o) ? buf[b - o] : 0;
        __syncthreads();
        buf[b] += t;
        __syncthreads();
    }
    pos[b * NBUCK + k] = buf[b] - v;
    if (b == NBLK - 1) cnt[k] = buf[b];
}

__global__ __launch_bounds__(256) void place_kernel(
    const int* __restrict__ ei, const int* __restrict__ pos,
    unsigned* __restrict__ bucketData)
{
    __shared__ int cursor[NBUCK];
    int blk = blockIdx.x, tid = threadIdx.x;
    for (int i = tid; i < NBUCK; i += 256) cursor[i] = pos[blk * NBUCK + i];
    __syncthreads();
    int start = blk * CHUNK, end = min(start + CHUNK, N_EDGES);
    for (int e = start + tid; e < end; e += 256) {
        int r = ei[e];
        int c = ei[N_EDGES + e];
        int k = r >> 7;
        int p = atomicAdd(&cursor[k], 1);   // LDS atomic, block-local
        bucketData[(size_t)k * BCAP + p] = ((unsigned)(r & 127) << 17) | (unsigned)c;
    }
}

__global__ __launch_bounds__(256) void bucket_count_kernel(
    const unsigned* __restrict__ bucketData, const int* __restrict__ cnt,
    int* __restrict__ deg, int* __restrict__ bpad)
{
    __shared__ int rc[128];
    __shared__ int red[4];
    int b = blockIdx.x, tid = threadIdx.x;
    int rowbase = b << 7;
    int nrows = min(128, N_NODES - rowbase);
    int cntb = cnt[b];
    if (tid < 128) rc[tid] = 0;
    __syncthreads();
    for (int e = tid; e < cntb; e += 256)
        atomicAdd(&rc[bucketData[(size_t)b * BCAP + e] >> 17], 1);
    __syncthreads();
    int v = 0;
    if (tid < nrows) {
        int d = rc[tid];
        deg[rowbase + tid] = d;
        v = pdeg_of(d);
    }
    #pragma unroll
    for (int o = 32; o > 0; o >>= 1) v += __shfl_down(v, o, 64);
    if ((tid & 63) == 0) red[tid >> 6] = v;
    __syncthreads();
    if (tid == 0) bpad[b] = red[0] + red[1] + red[2] + red[3];
}

__global__ __launch_bounds__(1024) void bucket_scan_kernel(
    const int* __restrict__ bpad, int* __restrict__ bbase)
{
    __shared__ int buf[1024];
    int tid = threadIdx.x;
    int own = (tid < NBUCK) ? bpad[tid] : 0;
    buf[tid] = own;
    __syncthreads();
    for (int o = 1; o < 1024; o <<= 1) {
        int t = (tid >= o) ? buf[tid - o] : 0;
        __syncthreads();
        buf[tid] += t;
        __syncthreads();
    }
    if (tid < NBUCK) bbase[tid] = buf[tid] - own;
}

__global__ __launch_bounds__(256) void bucket_emit_kernel(
    const unsigned* __restrict__ bucketData, const int* __restrict__ cnt,
    const int* __restrict__ bbase,
    int* __restrict__ off, int* __restrict__ colS)
{
    __shared__ int rc[128], rstart[128], rcur[128], sbuf[128];
    __shared__ int region[4096];
    int b = blockIdx.x, tid = threadIdx.x;
    int rowbase = b << 7;
    int nrows = min(128, N_NODES - rowbase);
    int cntb = cnt[b];
    int base = bbase[b];
    if (tid < 128) rc[tid] = 0;
    __syncthreads();
    for (int e = tid; e < cntb; e += 256)
        atomicAdd(&rc[bucketData[(size_t)b * BCAP + e] >> 17], 1);
    __syncthreads();
    int pd = (tid < nrows) ? pdeg_of(rc[tid]) : 0;
    if (tid < 128) sbuf[tid] = pd;
    __syncthreads();
    for (int o = 1; o < 128; o <<= 1) {
        int t = 0;
        if (tid < 128 && tid >= o) t = sbuf[tid - o];
        __syncthreads();
        if (tid < 128) sbuf[tid] += t;
        __syncthreads();
    }
    if (tid < 128) { rstart[tid] = sbuf[tid] - pd; rcur[tid] = sbuf[tid] - pd; }
    __syncthreads();
    int total = sbuf[127];
    for (int e = tid; e < cntb; e += 256) {
        unsigned p = bucketData[(size_t)b * BCAP + e];
        int lr = p >> 17;
        int c = p & 0x1FFFF;
        int pos = atomicAdd(&rcur[lr], 1);
        region[pos] = c * DF;
    }
    __syncthreads();
    for (int i = tid; i < nrows; i += 256) {
        int st = rstart[i] + rc[i];
        int en = rstart[i] + pdeg_of(rc[i]);
        int sent = (rowbase + i) * DF;
        for (int j = st; j < en; ++j) region[j] = sent;
    }
    __syncthreads();
    for (int k = tid; k < total; k += 256) colS[base + k] = region[k];
    if (tid < nrows) off[rowbase + tid] = base + rstart[tid];
    if (b == NBUCK - 1 && tid == 0) off[N_NODES] = base + total;
}

// ---------------------------------------------------------------------------
__global__ __launch_bounds__(256) void gstart_kernel(
    const int* __restrict__ batch, int* __restrict__ gstart,
    float* __restrict__ idsc, float* __restrict__ idsh)
{
    int g = blockIdx.x * 256 + threadIdx.x;
    if (g < 64) { idsc[g] = 1.0f; idsh[g] = 0.0f; }
    if (g > NGRAPH) return;
    if (g == NGRAPH) { gstart[g] = N_NODES; return; }
    int lo = 0, hi = N_NODES;
    while (lo < hi) {
        int mid = (lo + hi) >> 1;
        if (batch[mid] < g) lo = mid + 1; else hi = mid;
    }
    gstart[g] = lo;
}

// ---------------------------------------------------------------------------
// Pack W (fp32 [64][64], z@W) into MFMA B-fragment order, bf16.
// ---------------------------------------------------------------------------
__global__ __launch_bounds__(256) void pack_w_kernel(
    const float* __restrict__ W1, const float* __restrict__ W2,
    short* __restrict__ Wpk)
{
    int u = blockIdx.x;            // 0..5 = layer*2 + gemm
    int layer = u >> 1, gm = u & 1;
    const float* W = (gm ? W2 : W1) + layer * 4096;
    short* dst = Wpk + u * 4096;
    for (int idx = threadIdx.x; idx < 4096; idx += 256) {
        int i = idx & 7;
        int l = (idx >> 3) & 63;
        int rest = idx >> 9;       // nt*2+kt
        int kt = rest & 1, nt = rest >> 1;
        int k = kt * 32 + (l >> 4) * 8 + i;
        int n = nt * 16 + (l & 15);
        dst[idx] = f2bf(W[k * 64 + n]);
    }
}

// ---------------------------------------------------------------------------
// Fused GIN layer (MFMA). 8 waves/block, one 16-node tile per wave (max
// occupancy: LDS 34.8KB -> 4 blocks/CU -> 32 waves). Branchless padded
// gather (SALU addressing); prev-layer BN folded in.
// ---------------------------------------------------------------------------
template <bool BF16IN>
__global__ __launch_bounds__(512) void gin_layer_kernel(
    const void* __restrict__ zp_,
    const float* __restrict__ sc_in,
    const float* __restrict__ sh_in,
    const int* __restrict__ off,
    const int* __restrict__ deg,
    const int* __restrict__ colS,
    unsigned short* __restrict__ zout,  // bf16
    const short* __restrict__ Wpk,
    const float* __restrict__ b1,
    const float* __restrict__ b2,
    const float* __restrict__ gin_eps,
    const float* __restrict__ gin_bias,
    float* __restrict__ part_s,
    float* __restrict__ part_q)
{
    __shared__ __align__(16) short Wp1s[4096];
    __shared__ __align__(16) short Wp2s[4096];
    __shared__ __align__(16) short zs[8][16 * 72];

    const float* zpf = (const float*)zp_;
    const unsigned short* zpb = (const unsigned short*)zp_;

    int tid = threadIdx.x;
    {   // stage packed weights (16 KB), once per block
        const short4* s1 = (const short4*)Wpk;
        const short4* s2 = (const short4*)(Wpk + 4096);
        short4* d1 = (short4*)Wp1s;
        short4* d2 = (short4*)Wp2s;
        for (int i = tid; i < 1024; i += 512) { d1[i] = s1[i]; d2[i] = s2[i]; }
    }

    int w = tid >> 6, l = tid & 63;
    int lr = l & 15;
    int lk = l >> 4;
    float epsf = 1.0f + gin_eps[0];
    float scf = sc_in[l], shf = sh_in[l];
    float b1f[4], b2f[4], gbf[4];
    #pragma unroll
    for (int nt = 0; nt < 4; ++nt) {
        b1f[nt] = b1[nt * 16 + lr];
        b2f[nt] = b2[nt * 16 + lr];
        gbf[nt] = gin_bias[nt * 16 + lr];
    }
    float ssum[4] = {0, 0, 0, 0}, sq[4] = {0, 0, 0, 0};
    short* zw = zs[w];
    __syncthreads();

    int t = blockIdx.x * 8 + w;
    bool active = t < NTILES;
    int n0 = t * 16;

    if (active) {
        #pragma unroll 1
        for (int mp = 0; mp < 8; ++mp) {
            int nodeA = n0 + (mp << 1);
            int nodeB = nodeA + 1;
            int sA = __builtin_amdgcn_readfirstlane(off[nodeA]);
            int eA = __builtin_amdgcn_readfirstlane(off[nodeA + 1]);
            int dA = __builtin_amdgcn_readfirstlane(deg[nodeA]);
            int sB = __builtin_amdgcn_readfirstlane(off[nodeB]);
            int eB = __builtin_amdgcn_readfirstlane(off[nodeB + 1]);
            int dB = __builtin_amdgcn_readfirstlane(deg[nodeB]);
            float hnA, hnB;
            if (BF16IN) { hnA = bf2f(zpb[nodeA * DF + l]); hnB = bf2f(zpb[nodeB * DF + l]); }
            else        { hnA = zpf[nodeA * DF + l];       hnB = zpf[nodeB * DF + l]; }
            float vA[16], vB[16];
            #pragma unroll
            for (int j = 0; j < 16; ++j) {
                int co = __builtin_amdgcn_readfirstlane(colS[sA + j]);
                vA[j] = BF16IN ? bf2f(zpb[co + l]) : zpf[co + l];
            }
            #pragma unroll
            for (int j = 0; j < 16; ++j) {
                int co = __builtin_amdgcn_readfirstlane(colS[sB + j]);
                vB[j] = BF16IN ? bf2f(zpb[co + l]) : zpf[co + l];
            }
            float aA0 = (vA[0] + vA[1]) + (vA[2] + vA[3]);
            float aA1 = (vA[4] + vA[5]) + (vA[6] + vA[7]);
            float aA2 = (vA[8] + vA[9]) + (vA[10] + vA[11]);
            float aA3 = (vA[12] + vA[13]) + (vA[14] + vA[15]);
            float accA = (aA0 + aA1) + (aA2 + aA3);
            float aB0 = (vB[0] + vB[1]) + (vB[2] + vB[3]);
            float aB1 = (vB[4] + vB[5]) + (vB[6] + vB[7]);
            float aB2 = (vB[8] + vB[9]) + (vB[10] + vB[11]);
            float aB3 = (vB[12] + vB[13]) + (vB[14] + vB[15]);
            float accB = (aB0 + aB1) + (aB2 + aB3);
            for (int i = sA + 16; i < eA; i += 16) {
                #pragma unroll
                for (int j = 0; j < 16; ++j) {
                    int co = __builtin_amdgcn_readfirstlane(colS[i + j]);
                    accA += BF16IN ? bf2f(zpb[co + l]) : zpf[co + l];
                }
            }
            for (int i = sB + 16; i < eB; i += 16) {
                #pragma unroll
                for (int j = 0; j < 16; ++j) {
                    int co = __builtin_amdgcn_readfirstlane(colS[i + j]);
                    accB += BF16IN ? bf2f(zpb[co + l]) : zpf[co + l];
                }
            }
            float npA = (float)(eA - sA - dA);
            float npB = (float)(eB - sB - dB);
            float zfA = scf * ((epsf - npA) * hnA + accA) + (epsf + (float)dA) * shf;
            float zfB = scf * ((epsf - npB) * hnB + accB) + (epsf + (float)dB) * shf;
            zw[(mp * 2) * 72 + l] = f2bf(zfA);
            zw[(mp * 2 + 1) * 72 + l] = f2bf(zfB);
        }

        // ---- GEMM1 ----
        {
            bf16x8 a0 = *(const bf16x8*)&zw[lr * 72 + lk * 8];
            bf16x8 a1 = *(const bf16x8*)&zw[lr * 72 + 32 + lk * 8];
            #pragma unroll
            for (int nt = 0; nt < 4; ++nt) {
                f32x4 acc = {0.f, 0.f, 0.f, 0.f};
                bf16x8 bb0 = *(const bf16x8*)&Wp1s[((nt * 2 + 0) * 64 + l) * 8];
                bf16x8 bb1 = *(const bf16x8*)&Wp1s[((nt * 2 + 1) * 64 + l) * 8];
                acc = __builtin_amdgcn_mfma_f32_16x16x32_bf16(a0, bb0, acc, 0, 0, 0);
                acc = __builtin_amdgcn_mfma_f32_16x16x32_bf16(a1, bb1, acc, 0, 0, 0);
                #pragma unroll
                for (int r = 0; r < 4; ++r) {
                    float v = fmaxf(acc[r] + b1f[nt], 0.0f);
                    zw[(lk * 4 + r) * 72 + nt * 16 + lr] = f2bf(v);
                }
            }
        }

        // ---- GEMM2 + epilogue (store bf16, stats on rounded value) ----
        {
            bf16x8 a0 = *(const bf16x8*)&zw[lr * 72 + lk * 8];
            bf16x8 a1 = *(const bf16x8*)&zw[lr * 72 + 32 + lk * 8];
            #pragma unroll
            for (int nt = 0; nt < 4; ++nt) {
                f32x4 acc = {0.f, 0.f, 0.f, 0.f};
                bf16x8 bb0 = *(const bf16x8*)&Wp2s[((nt * 2 + 0) * 64 + l) * 8];
                bf16x8 bb1 = *(const bf16x8*)&Wp2s[((nt * 2 + 1) * 64 + l) * 8];
                acc = __builtin_amdgcn_mfma_f32_16x16x32_bf16(a0, bb0, acc, 0, 0, 0);
                acc = __builtin_amdgcn_mfma_f32_16x16x32_bf16(a1, bb1, acc, 0, 0, 0);
                #pragma unroll
                for (int r = 0; r < 4; ++r) {
                    float v = fmaxf(fmaxf(acc[r] + b2f[nt], 0.0f) + gbf[nt], 0.0f);
                    unsigned short vb = (unsigned short)f2bf(v);
                    zout[(n0 + lk * 4 + r) * DF + nt * 16 + lr] = vb;
                    float vr = bf2f(vb);
                    ssum[nt] += vr;
                    sq[nt] += vr * vr;
                }
            }
        }
    }

    #pragma unroll
    for (int nt = 0; nt < 4; ++nt) {
        float sv = ssum[nt], qv = sq[nt];
        sv += __shfl_xor(sv, 16, 64); sv += __shfl_xor(sv, 32, 64);
        qv += __shfl_xor(qv, 16, 64); qv += __shfl_xor(qv, 32, 64);
        if (l < 16) {
            part_s[(nt * 16 + l) * NWT + t] = sv;
            part_q[(nt * 16 + l) * NWT + t] = qv;
        }
    }
}

// ---------------------------------------------------------------------------
__global__ __launch_bounds__(256) void stat_reduce_kernel(
    const float* __restrict__ part_s, const float* __restrict__ part_q,
    const float* __restrict__ gamma, const float* __restrict__ beta,
    float* __restrict__ scale, float* __restrict__ shift)
{
    __shared__ double rs[4], rq[4];
    int f = blockIdx.x, tid = threadIdx.x;
    double s = 0.0, q = 0.0;
    for (int j = tid; j < NWT; j += 256) {
        s += (double)part_s[f * NWT + j];
        q += (double)part_q[f * NWT + j];
    }
    for (int o = 32; o > 0; o >>= 1) {
        s += __shfl_down(s, o, 64);
        q += __shfl_down(q, o, 64);
    }
    if ((tid & 63) == 0) { rs[tid >> 6] = s; rq[tid >> 6] = q; }
    __syncthreads();
    if (tid == 0) {
        double st = rs[0] + rs[1] + rs[2] + rs[3];
        double qt = rq[0] + rq[1] + rq[2] + rq[3];
        double mean = st / N_NODES;
        double var = qt / N_NODES - mean * mean;
        double inv = (double)gamma[f] / sqrt(var + BN_EPS);
        scale[f] = (float)inv;
        shift[f] = (float)((double)beta[f] - mean * inv);
    }
}

// ---------------------------------------------------------------------------
// Pool-only (bf16 z3): pooled[g] = sc * sum z3 + cnt(g) * sh
// ---------------------------------------------------------------------------
__global__ __launch_bounds__(256) void pool_kernel(
    const unsigned short* __restrict__ z,
    const float* __restrict__ scale,
    const float* __restrict__ shift,
    const int* __restrict__ gstart,
    float* __restrict__ pooled,
    int layerOff)
{
    __shared__ float red[4][64];
    int g = blockIdx.x;
    int tid = threadIdx.x;
    int w = tid >> 6, f = tid & 63;

    int s = gstart[g], e = gstart[g + 1];
    float acc = 0.0f;
    for (int node = s + w; node < e; node += 4)
        acc += bf2f(z[node * DF + f]);
    red[w][f] = acc;
    __syncthreads();
    if (w == 0)
        pooled[g * LDIM + layerOff + f] =
            scale[f] * (red[0][f] + red[1][f] + red[2][f] + red[3][f])
            + (float)(e - s) * shift[f];
}

// ---------------------------------------------------------------------------
// Fused projection head: out = relu(pooled@Wp1+bp1) @ Wp2 + bp2 (row-local)
// ---------------------------------------------------------------------------
__global__ __launch_bounds__(192) void proj_fused_kernel(
    const float* __restrict__ in,
    const float* __restrict__ Wp1, const float* __restrict__ bp1,
    const float* __restrict__ Wp2, const float* __restrict__ bp2,
    float* __restrict__ out)
{
    __shared__ float rowS[LDIM];
    __shared__ float hid[LDIM];
    int r = blockIdx.x;
    int c = threadIdx.x;
    rowS[c] = in[r * LDIM + c];
    __syncthreads();
    float acc = bp1[c];
    #pragma unroll 4
    for (int k = 0; k < LDIM; ++k) acc += rowS[k] * Wp1[k * LDIM + c];
    hid[c] = fmaxf(acc, 0.0f);
    __syncthreads();
    float acc2 = bp2[c];
    #pragma unroll 4
    for (int k = 0; k < LDIM; ++k) acc2 += hid[k] * Wp2[k * LDIM + c];
    out[r * LDIM + c] = acc2;
}

// ---------------------------------------------------------------------------
extern "C" void kernel_launch(void* const* d_in, const int* in_sizes, int n_in,
                              void* d_out, int out_size, void* d_ws, size_t ws_size,
                              hipStream_t stream)
{
    const float* x        = (const float*)d_in[0];
    const int*   ei       = (const int*)d_in[1];
    const int*   batch    = (const int*)d_in[2];
    const float* W1       = (const float*)d_in[3];
    const float* b1       = (const float*)d_in[4];
    const float* W2       = (const float*)d_in[5];
    const float* b2       = (const float*)d_in[6];
    const float* gin_eps  = (const float*)d_in[7];
    const float* gin_bias = (const float*)d_in[8];
    const float* gamma    = (const float*)d_in[9];
    const float* beta     = (const float*)d_in[10];
    const float* Wp1      = (const float*)d_in[11];
    const float* bp1      = (const float*)d_in[12];
    const float* Wp2      = (const float*)d_in[13];
    const float* bp2      = (const float*)d_in[14];
    float* out = (float*)d_out;

    // workspace layout
    unsigned short* zbufA = (unsigned short*)d_ws;          // N*64 bf16
    unsigned short* zbufB = zbufA + (size_t)N_NODES * DF;   // N*64 bf16
    float* pooled = (float*)(zbufB + (size_t)N_NODES * DF); // NGRAPH*LDIM
    float* scale = pooled + (size_t)NGRAPH * LDIM;          // 64
    float* shift = scale + 64;                              // 64
    float* idsc = shift + 64;                               // 64 (1.0)
    float* idsh = idsc + 64;                                // 64 (0.0)
    float* part_s = idsh + 64;                              // 64*NWT
    float* part_q = part_s + (size_t)64 * NWT;              // 64*NWT
    int* gstart = (int*)(part_q + (size_t)64 * NWT);        // NGRAPH+1
    int* deg  = gstart + NGRAPH + 1;                        // N
    int* off  = deg + N_NODES;                              // N+1
    int* colS = off + N_NODES + 1;                          // COLS_CAP
    int* hist = colS + COLS_CAP;                            // NBLK*NBUCK
    int* pos  = hist + NBLK * NBUCK;                        // NBLK*NBUCK
    int* cnt  = pos + NBLK * NBUCK;                         // NBUCK
    int* bpad = cnt + NBUCK;                                // NBUCK
    int* bbase = bpad + NBUCK;                              // NBUCK
    unsigned* bucketData = (unsigned*)(bbase + NBUCK);      // NBUCK*BCAP
    short* Wpk = (short*)(bucketData + (size_t)NBUCK * BCAP); // 6*4096 bf16

    // ---- counting-sort CSR build + graph segments + weight pack ----
    blk_hist_kernel<<<NBLK, 256, 0, stream>>>(ei, hist);
    blk_scan_kernel<<<NBUCK, NBLK, 0, stream>>>(hist, pos, cnt);
    place_kernel<<<NBLK, 256, 0, stream>>>(ei, pos, bucketData);
    bucket_count_kernel<<<NBUCK, 256, 0, stream>>>(bucketData, cnt, deg, bpad);
    bucket_scan_kernel<<<1, 1024, 0, stream>>>(bpad, bbase);
    bucket_emit_kernel<<<NBUCK, 256, 0, stream>>>(bucketData, cnt, bbase,
                                                  off, colS);
    gstart_kernel<<<3, 256, 0, stream>>>(batch, gstart, idsc, idsh);
    pack_w_kernel<<<6, 256, 0, stream>>>(W1, W2, Wpk);

    unsigned short* zbuf[2] = {zbufA, zbufB};
    const void* zprev = (const void*)x;
    const float* sc_in = idsc;
    const float* sh_in = idsh;
    for (int l = 0; l < 3; ++l) {
        unsigned short* zcur = zbuf[l & 1];
        if (l == 0)
            gin_layer_kernel<false><<<GIN_GRID, 512, 0, stream>>>(
                zprev, sc_in, sh_in, off, deg, colS, zcur,
                Wpk + (size_t)l * 8192,
                b1 + l * 64, b2 + l * 64, gin_eps + l, gin_bias + l * 64,
                part_s, part_q);
        else
            gin_layer_kernel<true><<<GIN_GRID, 512, 0, stream>>>(
                zprev, sc_in, sh_in, off, deg, colS, zcur,
                Wpk + (size_t)l * 8192,
                b1 + l * 64, b2 + l * 64, gin_eps + l, gin_bias + l * 64,
                part_s, part_q);

        stat_reduce_kernel<<<64, 256, 0, stream>>>(
            part_s, part_q, gamma + l * 64, beta + l * 64, scale, shift);

        pool_kernel<<<NGRAPH, 256, 0, stream>>>(
            zcur, scale, shift, gstart, pooled, l * 64);

        zprev = (const void*)zcur;
        sc_in = scale;
        sh_in = shift;
    }

    proj_fused_kernel<<<NGRAPH, LDIM, 0, stream>>>(pooled, Wp1, bp1, Wp2, bp2, out);
}

// Round 13
// 272.286 us; speedup vs baseline: 1.0227x; 1.0227x over previous
//
#include <hip/hip_runtime.h>

#define N_NODES 100000
#define N_EDGES 800000
#define DF 64
#define NGRAPH 512
#define LDIM 192   // L * D
#define BN_EPS 1e-5
#define NTILES 6250      // N_NODES / 16
#define GIN_GRID 782     // ceil(NTILES / 8 waves)
#define NWT (GIN_GRID * 8)
#define NPACKS 12500     // N_NODES / 8
#define COLS_CAP 2600000
#define NBUCK 782        // ceil(N_NODES / 128)
#define BCAP 2048
#define NBLK 128
#define CHUNK 6250       // N_EDGES / NBLK
#define REGION_CAP 6144  // per-bucket transposed region (ints)

typedef __attribute__((ext_vector_type(8))) short bf16x8;
typedef __attribute__((ext_vector_type(4))) float f32x4;

__device__ inline short f2bf(float x) {
    union { float f; unsigned u; } v; v.f = x;
    unsigned r = v.u + 0x7fff + ((v.u >> 16) & 1);   // RNE
    return (short)(r >> 16);
}
__device__ inline float bf2f(unsigned short u) {
    union { unsigned u; float f; } v; v.u = ((unsigned)u) << 16; return v.f;
}
__device__ inline float bflo(unsigned u) {
    union { unsigned x; float f; } v; v.x = u << 16; return v.f;
}
__device__ inline float bfhi(unsigned u) {
    union { unsigned x; float f; } v; v.x = u & 0xffff0000u; return v.f;
}

// ---------------------------------------------------------------------------
// x (fp32) -> bf16 copy
// ---------------------------------------------------------------------------
__global__ __launch_bounds__(256) void x2bf_kernel(
    const float* __restrict__ x, unsigned short* __restrict__ xb)
{
    int i = blockIdx.x * 256 + threadIdx.x;     // one per 8 elements
    const int total = N_NODES * DF / 8;
    if (i >= total) return;
    const float4* src = (const float4*)(x + (size_t)i * 8);
    float4 a = src[0], b = src[1];
    unsigned short u0 = (unsigned short)f2bf(a.x), u1 = (unsigned short)f2bf(a.y);
    unsigned short u2 = (unsigned short)f2bf(a.z), u3 = (unsigned short)f2bf(a.w);
    unsigned short u4 = (unsigned short)f2bf(b.x), u5 = (unsigned short)f2bf(b.y);
    unsigned short u6 = (unsigned short)f2bf(b.z), u7 = (unsigned short)f2bf(b.w);
    uint4 o;
    o.x = (unsigned)u0 | ((unsigned)u1 << 16);
    o.y = (unsigned)u2 | ((unsigned)u3 << 16);
    o.z = (unsigned)u4 | ((unsigned)u5 << 16);
    o.w = (unsigned)u6 | ((unsigned)u7 << 16);
    ((uint4*)xb)[i] = o;
}

// ---------------------------------------------------------------------------
// Counting-sort bucket build (no global atomics). bucket = row >> 7.
// ---------------------------------------------------------------------------
__global__ __launch_bounds__(256) void blk_hist_kernel(
    const int* __restrict__ ei, int* __restrict__ hist)
{
    __shared__ int hh[NBUCK];
    int blk = blockIdx.x, tid = threadIdx.x;
    for (int i = tid; i < NBUCK; i += 256) hh[i] = 0;
    __syncthreads();
    int start = blk * CHUNK, end = min(start + CHUNK, N_EDGES);
    for (int e = start + tid; e < end; e += 256)
        atomicAdd(&hh[ei[e] >> 7], 1);
    __syncthreads();
    for (int i = tid; i < NBUCK; i += 256) hist[blk * NBUCK + i] = hh[i];
}

__global__ __launch_bounds__(NBLK) void blk_scan_kernel(
    const int* __restrict__ hist, int* __restrict__ pos, int* __restrict__ cnt)
{
    __shared__ int buf[NBLK];
    int k = blockIdx.x, b = threadIdx.x;
    int v = hist[b * NBUCK + k];
    buf[b] = v;
    __syncthreads();
    for (int o = 1; o < NBLK; o <<= 1) {
        int t = (b >= o) ? buf[b - o] : 0;
        __syncthreads();
        buf[b] += t;
        __syncthreads();
    }
    pos[b * NBUCK + k] = buf[b] - v;
    if (b == NBLK - 1) cnt[k] = buf[b];
}

__global__ __launch_bounds__(256) void place_kernel(
    const int* __restrict__ ei, const int* __restrict__ pos,
    unsigned* __restrict__ bucketData)
{
    __shared__ int cursor[NBUCK];
    int blk = blockIdx.x, tid = threadIdx.x;
    for (int i = tid; i < NBUCK; i += 256) cursor[i] = pos[blk * NBUCK + i];
    __syncthreads();
    int start = blk * CHUNK, end = min(start + CHUNK, N_EDGES);
    for (int e = start + tid; e < end; e += 256) {
        int r = ei[e];
        int c = ei[N_EDGES + e];
        int k = r >> 7;
        int p = atomicAdd(&cursor[k], 1);   // LDS atomic, block-local
        bucketData[(size_t)k * BCAP + p] = ((unsigned)(r & 127) << 17) | (unsigned)c;
    }
}

// deg + per-bucket padded totals (pack-transposed widths: max of 8, round to 2)
__global__ __launch_bounds__(256) void bucket_count_kernel(
    const unsigned* __restrict__ bucketData, const int* __restrict__ cnt,
    int* __restrict__ deg, int* __restrict__ bpad)
{
    __shared__ int rc[128];
    __shared__ int wps[16];
    int b = blockIdx.x, tid = threadIdx.x;
    int rowbase = b << 7;
    int nrows = min(128, N_NODES - rowbase);
    int cntb = cnt[b];
    if (tid < 128) rc[tid] = 0;
    __syncthreads();
    for (int e = tid; e < cntb; e += 256)
        atomicAdd(&rc[bucketData[(size_t)b * BCAP + e] >> 17], 1);
    __syncthreads();
    if (tid < nrows) deg[rowbase + tid] = rc[tid];
    if (tid < 16) {
        int m = 0;
        #pragma unroll
        for (int i = 0; i < 8; ++i) m = max(m, rc[tid * 8 + i]);
        wps[tid] = (m + 1) & ~1;           // round up to multiple of 2
    }
    __syncthreads();
    if (tid == 0) {
        int s = 0;
        #pragma unroll
        for (int pk = 0; pk < 16; ++pk) s += 8 * wps[pk];
        bpad[b] = s;
    }
}

__global__ __launch_bounds__(1024) void bucket_scan_kernel(
    const int* __restrict__ bpad, int* __restrict__ bbase)
{
    __shared__ int buf[1024];
    int tid = threadIdx.x;
    int own = (tid < NBUCK) ? bpad[tid] : 0;
    buf[tid] = own;
    __syncthreads();
    for (int o = 1; o < 1024; o <<= 1) {
        int t = (tid >= o) ? buf[tid - o] : 0;
        __syncthreads();
        buf[tid] += t;
        __syncthreads();
    }
    if (tid < NBUCK) bbase[tid] = buf[tid] - own;
}

// Emit pack-transposed padded layout: colT[base + it*8 + g] for pack of 8 rows.
__global__ __launch_bounds__(256) void bucket_emit_kernel(
    const unsigned* __restrict__ bucketData, const int* __restrict__ cnt,
    const int* __restrict__ bbase,
    int* __restrict__ colT, int* __restrict__ offT, int* __restrict__ widT)
{
    __shared__ int rc[128], rcur[128];
    __shared__ int wps[16], pstart[16];
    __shared__ int region[REGION_CAP];
    __shared__ int totalS;
    int b = blockIdx.x, tid = threadIdx.x;
    int rowbase = b << 7;
    int nrows = min(128, N_NODES - rowbase);
    int cntb = cnt[b];
    int base = bbase[b];
    if (tid < 128) { rc[tid] = 0; rcur[tid] = 0; }
    __syncthreads();
    for (int e = tid; e < cntb; e += 256)
        atomicAdd(&rc[bucketData[(size_t)b * BCAP + e] >> 17], 1);
    __syncthreads();
    if (tid < 16) {
        int m = 0;
        #pragma unroll
        for (int i = 0; i < 8; ++i) m = max(m, rc[tid * 8 + i]);
        wps[tid] = (m + 1) & ~1;
    }
    __syncthreads();
    if (tid == 0) {
        int run = 0;
        #pragma unroll
        for (int pk = 0; pk < 16; ++pk) { pstart[pk] = run; run += 8 * wps[pk]; }
        totalS = run;
    }
    __syncthreads();
    int total = totalS;
    // real edges -> transposed slots
    for (int e = tid; e < cntb; e += 256) {
        unsigned p = bucketData[(size_t)b * BCAP + e];
        int lr = p >> 17;
        int c = p & 0x1FFFF;
        int slot = atomicAdd(&rcur[lr], 1);
        int pk = lr >> 3, g = lr & 7;
        region[pstart[pk] + slot * 8 + g] = c * DF;
    }
    __syncthreads();
    // pads point at the node's own row (corrected algebraically in gather)
    for (int i = tid; i < nrows; i += 256) {
        int pk = i >> 3, g = i & 7;
        int wp = wps[pk];
        int sent = (rowbase + i) * DF;
        for (int slot = rc[i]; slot < wp; ++slot)
            region[pstart[pk] + slot * 8 + g] = sent;
    }
    __syncthreads();
    for (int k = tid; k < total; k += 256) colT[base + k] = region[k];
    if (tid < 16 && tid * 8 < nrows) {
        offT[b * 16 + tid] = base + pstart[tid];
        widT[b * 16 + tid] = wps[tid];
    }
}

// ---------------------------------------------------------------------------
__global__ __launch_bounds__(256) void gstart_kernel(
    const int* __restrict__ batch, int* __restrict__ gstart,
    float* __restrict__ idsc, float* __restrict__ idsh)
{
    int g = blockIdx.x * 256 + threadIdx.x;
    if (g < 64) { idsc[g] = 1.0f; idsh[g] = 0.0f; }
    if (g > NGRAPH) return;
    if (g == NGRAPH) { gstart[g] = N_NODES; return; }
    int lo = 0, hi = N_NODES;
    while (lo < hi) {
        int mid = (lo + hi) >> 1;
        if (batch[mid] < g) lo = mid + 1; else hi = mid;
    }
    gstart[g] = lo;
}

// ---------------------------------------------------------------------------
__global__ __launch_bounds__(256) void pack_w_kernel(
    const float* __restrict__ W1, const float* __restrict__ W2,
    short* __restrict__ Wpk)
{
    int u = blockIdx.x;            // 0..5 = layer*2 + gemm
    int layer = u >> 1, gm = u & 1;
    const float* W = (gm ? W2 : W1) + layer * 4096;
    short* dst = Wpk + u * 4096;
    for (int idx = threadIdx.x; idx < 4096; idx += 256) {
        int i = idx & 7;
        int l = (idx >> 3) & 63;
        int rest = idx >> 9;       // nt*2+kt
        int kt = rest & 1, nt = rest >> 1;
        int k = kt * 32 + (l >> 4) * 8 + i;
        int n = nt * 16 + (l & 15);
        dst[idx] = f2bf(W[k * 64 + n]);
    }
}

// ---------------------------------------------------------------------------
// Fused GIN layer (MFMA). 8 waves/block, one 16-node tile (2 packs) per wave.
// Gather: 8 rows per wave-load (uint4/lane); lane l = (group g=l>>3 -> node,
// slot j=l&7 -> features 8j..8j+7). No cross-lane reduction. Pads = own row,
// corrected algebraically; prev-layer BN folded in.
// ---------------------------------------------------------------------------
__global__ __launch_bounds__(512) void gin_layer_kernel(
    const unsigned short* __restrict__ zpb,  // bf16 activations (xb for l=0)
    const float* __restrict__ sc_in,
    const float* __restrict__ sh_in,
    const int* __restrict__ offT,
    const int* __restrict__ widT,
    const int* __restrict__ deg,
    const int* __restrict__ colT,
    unsigned short* __restrict__ zout,       // bf16
    const short* __restrict__ Wpk,
    const float* __restrict__ b1,
    const float* __restrict__ b2,
    const float* __restrict__ gin_eps,
    const float* __restrict__ gin_bias,
    float* __restrict__ part_s,
    float* __restrict__ part_q)
{
    __shared__ __align__(16) short Wp1s[4096];
    __shared__ __align__(16) short Wp2s[4096];
    __shared__ __align__(16) short zs[8][16 * 80];   // stride 80 shorts/row

    int tid = threadIdx.x;
    {   // stage packed weights (16 KB), once per block
        const short4* s1 = (const short4*)Wpk;
        const short4* s2 = (const short4*)(Wpk + 4096);
        short4* d1 = (short4*)Wp1s;
        short4* d2 = (short4*)Wp2s;
        for (int i = tid; i < 1024; i += 512) { d1[i] = s1[i]; d2[i] = s2[i]; }
    }

    int w = tid >> 6, l = tid & 63;
    int lr = l & 15;       // MFMA indices
    int lk = l >> 4;
    int g8 = l >> 3;       // gather group (node within pack)
    int j8 = l & 7;        // feature slot (features 8*j8 .. 8*j8+7)
    float epsf = 1.0f + gin_eps[0];
    float b1f[4], b2f[4], gbf[4];
    #pragma unroll
    for (int nt = 0; nt < 4; ++nt) {
        b1f[nt] = b1[nt * 16 + lr];
        b2f[nt] = b2[nt * 16 + lr];
        gbf[nt] = gin_bias[nt * 16 + lr];
    }
    float4 sca = *(const float4*)&sc_in[j8 * 8];
    float4 scb = *(const float4*)&sc_in[j8 * 8 + 4];
    float4 sha = *(const float4*)&sh_in[j8 * 8];
    float4 shb = *(const float4*)&sh_in[j8 * 8 + 4];
    float ssum[4] = {0, 0, 0, 0}, sq[4] = {0, 0, 0, 0};
    short* zw = zs[w];
    __syncthreads();

    int t = blockIdx.x * 8 + w;
    bool active = t < NTILES;

    if (active) {
        // ---- gather: two packs of 8 nodes ----
        #pragma unroll
        for (int half = 0; half < 2; ++half) {
            int p = t * 2 + half;
            int nP0 = p * 8;
            int sP = __builtin_amdgcn_readfirstlane(offT[p]);
            int wP = __builtin_amdgcn_readfirstlane(widT[p]);
            float acc[8];
            #pragma unroll
            for (int i = 0; i < 8; ++i) acc[i] = 0.0f;
            #pragma unroll 1
            for (int it = 0; it < wP; it += 2) {
                int co0 = colT[sP + it * 8 + g8];
                int co1 = colT[sP + it * 8 + 8 + g8];
                uint4 v0 = *(const uint4*)(zpb + co0 + j8 * 8);
                uint4 v1 = *(const uint4*)(zpb + co1 + j8 * 8);
                acc[0] += bflo(v0.x) + bflo(v1.x);
                acc[1] += bfhi(v0.x) + bfhi(v1.x);
                acc[2] += bflo(v0.y) + bflo(v1.y);
                acc[3] += bfhi(v0.y) + bfhi(v1.y);
                acc[4] += bflo(v0.z) + bflo(v1.z);
                acc[5] += bfhi(v0.z) + bfhi(v1.z);
                acc[6] += bflo(v0.w) + bflo(v1.w);
                acc[7] += bfhi(v0.w) + bfhi(v1.w);
            }
            int node = nP0 + g8;
            int d = deg[node];
            uint4 hv = *(const uint4*)(zpb + node * DF + j8 * 8);
            float hn[8] = { bflo(hv.x), bfhi(hv.x), bflo(hv.y), bfhi(hv.y),
                            bflo(hv.z), bfhi(hv.z), bflo(hv.w), bfhi(hv.w) };
            float np = (float)(wP - d);
            float em = epsf - np;
            float dh = epsf + (float)d;
            float scv[8] = { sca.x, sca.y, sca.z, sca.w, scb.x, scb.y, scb.z, scb.w };
            float shv[8] = { sha.x, sha.y, sha.z, sha.w, shb.x, shb.y, shb.z, shb.w };
            unsigned short us[8];
            #pragma unroll
            for (int i = 0; i < 8; ++i) {
                float zf = scv[i] * (em * hn[i] + acc[i]) + dh * shv[i];
                us[i] = (unsigned short)f2bf(zf);
            }
            uint4 zpk;
            zpk.x = (unsigned)us[0] | ((unsigned)us[1] << 16);
            zpk.y = (unsigned)us[2] | ((unsigned)us[3] << 16);
            zpk.z = (unsigned)us[4] | ((unsigned)us[5] << 16);
            zpk.w = (unsigned)us[6] | ((unsigned)us[7] << 16);
            *(uint4*)&zw[(half * 8 + g8) * 80 + j8 * 8] = zpk;
        }

        // ---- GEMM1: z1 = relu(z @ W1 + b1)  (overwrites zw rows) ----
        {
            bf16x8 a0 = *(const bf16x8*)&zw[lr * 80 + lk * 8];
            bf16x8 a1 = *(const bf16x8*)&zw[lr * 80 + 32 + lk * 8];
            #pragma unroll
            for (int nt = 0; nt < 4; ++nt) {
                f32x4 acc = {0.f, 0.f, 0.f, 0.f};
                bf16x8 bb0 = *(const bf16x8*)&Wp1s[((nt * 2 + 0) * 64 + l) * 8];
                bf16x8 bb1 = *(const bf16x8*)&Wp1s[((nt * 2 + 1) * 64 + l) * 8];
                acc = __builtin_amdgcn_mfma_f32_16x16x32_bf16(a0, bb0, acc, 0, 0, 0);
                acc = __builtin_amdgcn_mfma_f32_16x16x32_bf16(a1, bb1, acc, 0, 0, 0);
                #pragma unroll
                for (int r = 0; r < 4; ++r) {
                    float v = fmaxf(acc[r] + b1f[nt], 0.0f);
                    zw[(lk * 4 + r) * 80 + nt * 16 + lr] = f2bf(v);
                }
            }
        }

        // ---- GEMM2 + epilogue (store bf16, stats on rounded value) ----
        {
            int n0 = t * 16;
            bf16x8 a0 = *(const bf16x8*)&zw[lr * 80 + lk * 8];
            bf16x8 a1 = *(const bf16x8*)&zw[lr * 80 + 32 + lk * 8];
            #pragma unroll
            for (int nt = 0; nt < 4; ++nt) {
                f32x4 acc = {0.f, 0.f, 0.f, 0.f};
                bf16x8 bb0 = *(const bf16x8*)&Wp2s[((nt * 2 + 0) * 64 + l) * 8];
                bf16x8 bb1 = *(const bf16x8*)&Wp2s[((nt * 2 + 1) * 64 + l) * 8];
                acc = __builtin_amdgcn_mfma_f32_16x16x32_bf16(a0, bb0, acc, 0, 0, 0);
                acc = __builtin_amdgcn_mfma_f32_16x16x32_bf16(a1, bb1, acc, 0, 0, 0);
                #pragma unroll
                for (int r = 0; r < 4; ++r) {
                    float v = fmaxf(fmaxf(acc[r] + b2f[nt], 0.0f) + gbf[nt], 0.0f);
                    unsigned short vb = (unsigned short)f2bf(v);
                    zout[(n0 + lk * 4 + r) * DF + nt * 16 + lr] = vb;
                    float vr = bf2f(vb);
                    ssum[nt] += vr;
                    sq[nt] += vr * vr;
                }
            }
        }
    }

    #pragma unroll
    for (int nt = 0; nt < 4; ++nt) {
        float sv = ssum[nt], qv = sq[nt];
        sv += __shfl_xor(sv, 16, 64); sv += __shfl_xor(sv, 32, 64);
        qv += __shfl_xor(qv, 16, 64); qv += __shfl_xor(qv, 32, 64);
        if (l < 16) {
            part_s[(nt * 16 + l) * NWT + t] = sv;
            part_q[(nt * 16 + l) * NWT + t] = qv;
        }
    }
}

// ---------------------------------------------------------------------------
__global__ __launch_bounds__(256) void stat_reduce_kernel(
    const float* __restrict__ part_s, const float* __restrict__ part_q,
    const float* __restrict__ gamma, const float* __restrict__ beta,
    float* __restrict__ scale, float* __restrict__ shift)
{
    __shared__ double rs[4], rq[4];
    int f = blockIdx.x, tid = threadIdx.x;
    double s = 0.0, q = 0.0;
    for (int j = tid; j < NWT; j += 256) {
        s += (double)part_s[f * NWT + j];
        q += (double)part_q[f * NWT + j];
    }
    for (int o = 32; o > 0; o >>= 1) {
        s += __shfl_down(s, o, 64);
        q += __shfl_down(q, o, 64);
    }
    if ((tid & 63) == 0) { rs[tid >> 6] = s; rq[tid >> 6] = q; }
    __syncthreads();
    if (tid == 0) {
        double st = rs[0] + rs[1] + rs[2] + rs[3];
        double qt = rq[0] + rq[1] + rq[2] + rq[3];
        double mean = st / N_NODES;
        double var = qt / N_NODES - mean * mean;
        double inv = (double)gamma[f] / sqrt(var + BN_EPS);
        scale[f] = (float)inv;
        shift[f] = (float)((double)beta[f] - mean * inv);
    }
}

// ---------------------------------------------------------------------------
__global__ __launch_bounds__(256) void pool_kernel(
    const unsigned short* __restrict__ z,
    const float* __restrict__ scale,
    const float* __restrict__ shift,
    const int* __restrict__ gstart,
    float* __restrict__ pooled,
    int layerOff)
{
    __shared__ float red[4][64];
    int g = blockIdx.x;
    int tid = threadIdx.x;
    int w = tid >> 6, f = tid & 63;

    int s = gstart[g], e = gstart[g + 1];
    float acc = 0.0f;
    for (int node = s + w; node < e; node += 4)
        acc += bf2f(z[node * DF + f]);
    red[w][f] = acc;
    __syncthreads();
    if (w == 0)
        pooled[g * LDIM + layerOff + f] =
            scale[f] * (red[0][f] + red[1][f] + red[2][f] + red[3][f])
            + (float)(e - s) * shift[f];
}

// ---------------------------------------------------------------------------
__global__ __launch_bounds__(192) void proj_fused_kernel(
    const float* __restrict__ in,
    const float* __restrict__ Wp1, const float* __restrict__ bp1,
    const float* __restrict__ Wp2, const float* __restrict__ bp2,
    float* __restrict__ out)
{
    __shared__ float rowS[LDIM];
    __shared__ float hid[LDIM];
    int r = blockIdx.x;
    int c = threadIdx.x;
    rowS[c] = in[r * LDIM + c];
    __syncthreads();
    float acc = bp1[c];
    #pragma unroll 4
    for (int k = 0; k < LDIM; ++k) acc += rowS[k] * Wp1[k * LDIM + c];
    hid[c] = fmaxf(acc, 0.0f);
    __syncthreads();
    float acc2 = bp2[c];
    #pragma unroll 4
    for (int k = 0; k < LDIM; ++k) acc2 += hid[k] * Wp2[k * LDIM + c];
    out[r * LDIM + c] = acc2;
}

// ---------------------------------------------------------------------------
extern "C" void kernel_launch(void* const* d_in, const int* in_sizes, int n_in,
                              void* d_out, int out_size, void* d_ws, size_t ws_size,
                              hipStream_t stream)
{
    const float* x        = (const float*)d_in[0];
    const int*   ei       = (const int*)d_in[1];
    const int*   batch    = (const int*)d_in[2];
    const float* W1       = (const float*)d_in[3];
    const float* b1       = (const float*)d_in[4];
    const float* W2       = (const float*)d_in[5];
    const float* b2       = (const float*)d_in[6];
    const float* gin_eps  = (const float*)d_in[7];
    const float* gin_bias = (const float*)d_in[8];
    const float* gamma    = (const float*)d_in[9];
    const float* beta     = (const float*)d_in[10];
    const float* Wp1      = (const float*)d_in[11];
    const float* bp1      = (const float*)d_in[12];
    const float* Wp2      = (const float*)d_in[13];
    const float* bp2      = (const float*)d_in[14];
    float* out = (float*)d_out;

    // workspace layout
    unsigned short* xb    = (unsigned short*)d_ws;          // N*64 bf16
    unsigned short* zbufA = xb + (size_t)N_NODES * DF;      // N*64 bf16
    unsigned short* zbufB = zbufA + (size_t)N_NODES * DF;   // N*64 bf16
    float* pooled = (float*)(zbufB + (size_t)N_NODES * DF); // NGRAPH*LDIM
    float* scale = pooled + (size_t)NGRAPH * LDIM;          // 64
    float* shift = scale + 64;                              // 64
    float* idsc = shift + 64;                               // 64 (1.0)
    float* idsh = idsc + 64;                                // 64 (0.0)
    float* part_s = idsh + 64;                              // 64*NWT
    float* part_q = part_s + (size_t)64 * NWT;              // 64*NWT
    int* gstart = (int*)(part_q + (size_t)64 * NWT);        // NGRAPH+1
    int* deg  = gstart + NGRAPH + 1;                        // N
    int* offT = deg + N_NODES;                              // 16*NBUCK
    int* widT = offT + 16 * NBUCK;                          // 16*NBUCK
    int* colT = widT + 16 * NBUCK;                          // COLS_CAP
    int* hist = colT + COLS_CAP;                            // NBLK*NBUCK
    int* pos  = hist + NBLK * NBUCK;                        // NBLK*NBUCK
    int* cnt  = pos + NBLK * NBUCK;                         // NBUCK
    int* bpad = cnt + NBUCK;                                // NBUCK
    int* bbase = bpad + NBUCK;                              // NBUCK
    unsigned* bucketData = (unsigned*)(bbase + NBUCK);      // NBUCK*BCAP
    short* Wpk = (short*)(bucketData + (size_t)NBUCK * BCAP); // 6*4096 bf16

    // ---- setup: x->bf16, counting-sort transposed CSR, segments, weights ----
    x2bf_kernel<<<(N_NODES * DF / 8 + 255) / 256, 256, 0, stream>>>(x, xb);
    blk_hist_kernel<<<NBLK, 256, 0, stream>>>(ei, hist);
    blk_scan_kernel<<<NBUCK, NBLK, 0, stream>>>(hist, pos, cnt);
    place_kernel<<<NBLK, 256, 0, stream>>>(ei, pos, bucketData);
    bucket_count_kernel<<<NBUCK, 256, 0, stream>>>(bucketData, cnt, deg, bpad);
    bucket_scan_kernel<<<1, 1024, 0, stream>>>(bpad, bbase);
    bucket_emit_kernel<<<NBUCK, 256, 0, stream>>>(bucketData, cnt, bbase,
                                                  colT, offT, widT);
    gstart_kernel<<<3, 256, 0, stream>>>(batch, gstart, idsc, idsh);
    pack_w_kernel<<<6, 256, 0, stream>>>(W1, W2, Wpk);

    unsigned short* zbuf[2] = {zbufA, zbufB};
    const unsigned short* zprev = xb;
    const float* sc_in = idsc;
    const float* sh_in = idsh;
    for (int l = 0; l < 3; ++l) {
        unsigned short* zcur = zbuf[l & 1];
        gin_layer_kernel<<<GIN_GRID, 512, 0, stream>>>(
            zprev, sc_in, sh_in, offT, widT, deg, colT, zcur,
            Wpk + (size_t)l * 8192,
            b1 + l * 64, b2 + l * 64, gin_eps + l, gin_bias + l * 64,
            part_s, part_q);

        stat_reduce_kernel<<<64, 256, 0, stream>>>(
            part_s, part_q, gamma + l * 64, beta + l * 64, scale, shift);

        pool_kernel<<<NGRAPH, 256, 0, stream>>>(
            zcur, scale, shift, gstart, pooled, l * 64);

        zprev = zcur;
        sc_in = scale;
        sh_in = shift;
    }

    proj_fused_kernel<<<NGRAPH, LDIM, 0, stream>>>(pooled, Wp1, bp1, Wp2, bp2, out);
}

// Round 14
// 265.536 us; speedup vs baseline: 1.0487x; 1.0254x over previous
//
#include <hip/hip_runtime.h>

#define N_NODES 100000
#define N_EDGES 800000
#define DF 64
#define NGRAPH 512
#define LDIM 192   // L * D
#define BN_EPS 1e-5
#define NTILES 6250      // N_NODES / 16
#define GIN_GRID 782     // ceil(NTILES / 8 waves)
#define NWT (GIN_GRID * 8)
#define NPACKS 12500     // N_NODES / 8
#define COLS_CAP 2600000
#define NBUCK 782        // ceil(N_NODES / 128)
#define BCAP 2048
#define NBLK 128
#define CHUNK 6250       // N_EDGES / NBLK
#define REGION_CAP 6144  // per-bucket transposed region (ints)
#define PROJ_ROWS 8

typedef __attribute__((ext_vector_type(8))) short bf16x8;
typedef __attribute__((ext_vector_type(4))) float f32x4;

__device__ inline short f2bf(float x) {
    union { float f; unsigned u; } v; v.f = x;
    unsigned r = v.u + 0x7fff + ((v.u >> 16) & 1);   // RNE
    return (short)(r >> 16);
}
__device__ inline float bf2f(unsigned short u) {
    union { unsigned u; float f; } v; v.u = ((unsigned)u) << 16; return v.f;
}
__device__ inline float bflo(unsigned u) {
    union { unsigned x; float f; } v; v.x = u << 16; return v.f;
}
__device__ inline float bfhi(unsigned u) {
    union { unsigned x; float f; } v; v.x = u & 0xffff0000u; return v.f;
}

// ---------------------------------------------------------------------------
// x (fp32) -> bf16 copy
// ---------------------------------------------------------------------------
__global__ __launch_bounds__(256) void x2bf_kernel(
    const float* __restrict__ x, unsigned short* __restrict__ xb)
{
    int i = blockIdx.x * 256 + threadIdx.x;     // one per 8 elements
    const int total = N_NODES * DF / 8;
    if (i >= total) return;
    const float4* src = (const float4*)(x + (size_t)i * 8);
    float4 a = src[0], b = src[1];
    unsigned short u0 = (unsigned short)f2bf(a.x), u1 = (unsigned short)f2bf(a.y);
    unsigned short u2 = (unsigned short)f2bf(a.z), u3 = (unsigned short)f2bf(a.w);
    unsigned short u4 = (unsigned short)f2bf(b.x), u5 = (unsigned short)f2bf(b.y);
    unsigned short u6 = (unsigned short)f2bf(b.z), u7 = (unsigned short)f2bf(b.w);
    uint4 o;
    o.x = (unsigned)u0 | ((unsigned)u1 << 16);
    o.y = (unsigned)u2 | ((unsigned)u3 << 16);
    o.z = (unsigned)u4 | ((unsigned)u5 << 16);
    o.w = (unsigned)u6 | ((unsigned)u7 << 16);
    ((uint4*)xb)[i] = o;
}

// ---------------------------------------------------------------------------
// Counting-sort bucket build (no global atomics). bucket = row >> 7.
// ---------------------------------------------------------------------------
__global__ __launch_bounds__(256) void blk_hist_kernel(
    const int* __restrict__ ei, int* __restrict__ hist)
{
    __shared__ int hh[NBUCK];
    int blk = blockIdx.x, tid = threadIdx.x;
    for (int i = tid; i < NBUCK; i += 256) hh[i] = 0;
    __syncthreads();
    int start = blk * CHUNK, end = min(start + CHUNK, N_EDGES);
    for (int e = start + tid; e < end; e += 256)
        atomicAdd(&hh[ei[e] >> 7], 1);
    __syncthreads();
    for (int i = tid; i < NBUCK; i += 256) hist[blk * NBUCK + i] = hh[i];
}

__global__ __launch_bounds__(NBLK) void blk_scan_kernel(
    const int* __restrict__ hist, int* __restrict__ pos, int* __restrict__ cnt)
{
    __shared__ int buf[NBLK];
    int k = blockIdx.x, b = threadIdx.x;
    int v = hist[b * NBUCK + k];
    buf[b] = v;
    __syncthreads();
    for (int o = 1; o < NBLK; o <<= 1) {
        int t = (b >= o) ? buf[b - o] : 0;
        __syncthreads();
        buf[b] += t;
        __syncthreads();
    }
    pos[b * NBUCK + k] = buf[b] - v;
    if (b == NBLK - 1) cnt[k] = buf[b];
}

__global__ __launch_bounds__(256) void place_kernel(
    const int* __restrict__ ei, const int* __restrict__ pos,
    unsigned* __restrict__ bucketData)
{
    __shared__ int cursor[NBUCK];
    int blk = blockIdx.x, tid = threadIdx.x;
    for (int i = tid; i < NBUCK; i += 256) cursor[i] = pos[blk * NBUCK + i];
    __syncthreads();
    int start = blk * CHUNK, end = min(start + CHUNK, N_EDGES);
    for (int e = start + tid; e < end; e += 256) {
        int r = ei[e];
        int c = ei[N_EDGES + e];
        int k = r >> 7;
        int p = atomicAdd(&cursor[k], 1);   // LDS atomic, block-local
        bucketData[(size_t)k * BCAP + p] = ((unsigned)(r & 127) << 17) | (unsigned)c;
    }
}

// deg + per-bucket padded totals (pack-transposed widths: max of 8, round to 2)
__global__ __launch_bounds__(256) void bucket_count_kernel(
    const unsigned* __restrict__ bucketData, const int* __restrict__ cnt,
    int* __restrict__ deg, int* __restrict__ bpad)
{
    __shared__ int rc[128];
    __shared__ int wps[16];
    int b = blockIdx.x, tid = threadIdx.x;
    int rowbase = b << 7;
    int nrows = min(128, N_NODES - rowbase);
    int cntb = cnt[b];
    if (tid < 128) rc[tid] = 0;
    __syncthreads();
    for (int e = tid; e < cntb; e += 256)
        atomicAdd(&rc[bucketData[(size_t)b * BCAP + e] >> 17], 1);
    __syncthreads();
    if (tid < nrows) deg[rowbase + tid] = rc[tid];
    if (tid < 16) {
        int m = 0;
        #pragma unroll
        for (int i = 0; i < 8; ++i) m = max(m, rc[tid * 8 + i]);
        wps[tid] = (m + 1) & ~1;           // round up to multiple of 2
    }
    __syncthreads();
    if (tid == 0) {
        int s = 0;
        #pragma unroll
        for (int pk = 0; pk < 16; ++pk) s += 8 * wps[pk];
        bpad[b] = s;
    }
}

__global__ __launch_bounds__(1024) void bucket_scan_kernel(
    const int* __restrict__ bpad, int* __restrict__ bbase)
{
    __shared__ int buf[1024];
    int tid = threadIdx.x;
    int own = (tid < NBUCK) ? bpad[tid] : 0;
    buf[tid] = own;
    __syncthreads();
    for (int o = 1; o < 1024; o <<= 1) {
        int t = (tid >= o) ? buf[tid - o] : 0;
        __syncthreads();
        buf[tid] += t;
        __syncthreads();
    }
    if (tid < NBUCK) bbase[tid] = buf[tid] - own;
}

// Emit pack-transposed padded layout: colT[base + it*8 + g] for pack of 8 rows.
__global__ __launch_bounds__(256) void bucket_emit_kernel(
    const unsigned* __restrict__ bucketData, const int* __restrict__ cnt,
    const int* __restrict__ bbase,
    int* __restrict__ colT, int* __restrict__ offT, int* __restrict__ widT)
{
    __shared__ int rc[128], rcur[128];
    __shared__ int wps[16], pstart[16];
    __shared__ int region[REGION_CAP];
    __shared__ int totalS;
    int b = blockIdx.x, tid = threadIdx.x;
    int rowbase = b << 7;
    int nrows = min(128, N_NODES - rowbase);
    int cntb = cnt[b];
    int base = bbase[b];
    if (tid < 128) { rc[tid] = 0; rcur[tid] = 0; }
    __syncthreads();
    for (int e = tid; e < cntb; e += 256)
        atomicAdd(&rc[bucketData[(size_t)b * BCAP + e] >> 17], 1);
    __syncthreads();
    if (tid < 16) {
        int m = 0;
        #pragma unroll
        for (int i = 0; i < 8; ++i) m = max(m, rc[tid * 8 + i]);
        wps[tid] = (m + 1) & ~1;
    }
    __syncthreads();
    if (tid == 0) {
        int run = 0;
        #pragma unroll
        for (int pk = 0; pk < 16; ++pk) { pstart[pk] = run; run += 8 * wps[pk]; }
        totalS = run;
    }
    __syncthreads();
    int total = totalS;
    // real edges -> transposed slots
    for (int e = tid; e < cntb; e += 256) {
        unsigned p = bucketData[(size_t)b * BCAP + e];
        int lr = p >> 17;
        int c = p & 0x1FFFF;
        int slot = atomicAdd(&rcur[lr], 1);
        int pk = lr >> 3, g = lr & 7;
        region[pstart[pk] + slot * 8 + g] = c * DF;
    }
    __syncthreads();
    // pads point at the node's own row (corrected algebraically in gather)
    for (int i = tid; i < nrows; i += 256) {
        int pk = i >> 3, g = i & 7;
        int wp = wps[pk];
        int sent = (rowbase + i) * DF;
        for (int slot = rc[i]; slot < wp; ++slot)
            region[pstart[pk] + slot * 8 + g] = sent;
    }
    __syncthreads();
    for (int k = tid; k < total; k += 256) colT[base + k] = region[k];
    if (tid < 16 && tid * 8 < nrows) {
        offT[b * 16 + tid] = base + pstart[tid];
        widT[b * 16 + tid] = wps[tid];
    }
}

// ---------------------------------------------------------------------------
__global__ __launch_bounds__(256) void gstart_kernel(
    const int* __restrict__ batch, int* __restrict__ gstart,
    float* __restrict__ idsc, float* __restrict__ idsh)
{
    int g = blockIdx.x * 256 + threadIdx.x;
    if (g < 64) { idsc[g] = 1.0f; idsh[g] = 0.0f; }
    if (g > NGRAPH) return;
    if (g == NGRAPH) { gstart[g] = N_NODES; return; }
    int lo = 0, hi = N_NODES;
    while (lo < hi) {
        int mid = (lo + hi) >> 1;
        if (batch[mid] < g) lo = mid + 1; else hi = mid;
    }
    gstart[g] = lo;
}

// ---------------------------------------------------------------------------
__global__ __launch_bounds__(256) void pack_w_kernel(
    const float* __restrict__ W1, const float* __restrict__ W2,
    short* __restrict__ Wpk)
{
    int u = blockIdx.x;            // 0..5 = layer*2 + gemm
    int layer = u >> 1, gm = u & 1;
    const float* W = (gm ? W2 : W1) + layer * 4096;
    short* dst = Wpk + u * 4096;
    for (int idx = threadIdx.x; idx < 4096; idx += 256) {
        int i = idx & 7;
        int l = (idx >> 3) & 63;
        int rest = idx >> 9;       // nt*2+kt
        int kt = rest & 1, nt = rest >> 1;
        int k = kt * 32 + (l >> 4) * 8 + i;
        int n = nt * 16 + (l & 15);
        dst[idx] = f2bf(W[k * 64 + n]);
    }
}

// ---------------------------------------------------------------------------
// Fused GIN layer (MFMA). 8 waves/block, one 16-node tile (2 packs) per wave.
// Gather: 8 rows per wave-load (uint4/lane); lane l = (group g=l>>3 -> node,
// slot j=l&7 -> features 8j..8j+7). No cross-lane reduction. Pads = own row,
// corrected algebraically; prev-layer BN folded in.
// ---------------------------------------------------------------------------
__global__ __launch_bounds__(512) void gin_layer_kernel(
    const unsigned short* __restrict__ zpb,  // bf16 activations (xb for l=0)
    const float* __restrict__ sc_in,
    const float* __restrict__ sh_in,
    const int* __restrict__ offT,
    const int* __restrict__ widT,
    const int* __restrict__ deg,
    const int* __restrict__ colT,
    unsigned short* __restrict__ zout,       // bf16
    const short* __restrict__ Wpk,
    const float* __restrict__ b1,
    const float* __restrict__ b2,
    const float* __restrict__ gin_eps,
    const float* __restrict__ gin_bias,
    float* __restrict__ part_s,
    float* __restrict__ part_q)
{
    __shared__ __align__(16) short Wp1s[4096];
    __shared__ __align__(16) short Wp2s[4096];
    __shared__ __align__(16) short zs[8][16 * 80];   // stride 80 shorts/row

    int tid = threadIdx.x;
    {   // stage packed weights (16 KB), once per block
        const short4* s1 = (const short4*)Wpk;
        const short4* s2 = (const short4*)(Wpk + 4096);
        short4* d1 = (short4*)Wp1s;
        short4* d2 = (short4*)Wp2s;
        for (int i = tid; i < 1024; i += 512) { d1[i] = s1[i]; d2[i] = s2[i]; }
    }

    int w = tid >> 6, l = tid & 63;
    int lr = l & 15;       // MFMA indices
    int lk = l >> 4;
    int g8 = l >> 3;       // gather group (node within pack)
    int j8 = l & 7;        // feature slot (features 8*j8 .. 8*j8+7)
    float epsf = 1.0f + gin_eps[0];
    float b1f[4], b2f[4], gbf[4];
    #pragma unroll
    for (int nt = 0; nt < 4; ++nt) {
        b1f[nt] = b1[nt * 16 + lr];
        b2f[nt] = b2[nt * 16 + lr];
        gbf[nt] = gin_bias[nt * 16 + lr];
    }
    float4 sca = *(const float4*)&sc_in[j8 * 8];
    float4 scb = *(const float4*)&sc_in[j8 * 8 + 4];
    float4 sha = *(const float4*)&sh_in[j8 * 8];
    float4 shb = *(const float4*)&sh_in[j8 * 8 + 4];
    float ssum[4] = {0, 0, 0, 0}, sq[4] = {0, 0, 0, 0};
    short* zw = zs[w];
    __syncthreads();

    int t = blockIdx.x * 8 + w;
    bool active = t < NTILES;

    if (active) {
        // ---- gather: two packs of 8 nodes ----
        #pragma unroll
        for (int half = 0; half < 2; ++half) {
            int p = t * 2 + half;
            int nP0 = p * 8;
            int sP = __builtin_amdgcn_readfirstlane(offT[p]);
            int wP = __builtin_amdgcn_readfirstlane(widT[p]);
            float acc[8];
            #pragma unroll
            for (int i = 0; i < 8; ++i) acc[i] = 0.0f;
            #pragma unroll 1
            for (int it = 0; it < wP; it += 2) {
                int co0 = colT[sP + it * 8 + g8];
                int co1 = colT[sP + it * 8 + 8 + g8];
                uint4 v0 = *(const uint4*)(zpb + co0 + j8 * 8);
                uint4 v1 = *(const uint4*)(zpb + co1 + j8 * 8);
                acc[0] += bflo(v0.x) + bflo(v1.x);
                acc[1] += bfhi(v0.x) + bfhi(v1.x);
                acc[2] += bflo(v0.y) + bflo(v1.y);
                acc[3] += bfhi(v0.y) + bfhi(v1.y);
                acc[4] += bflo(v0.z) + bflo(v1.z);
                acc[5] += bfhi(v0.z) + bfhi(v1.z);
                acc[6] += bflo(v0.w) + bflo(v1.w);
                acc[7] += bfhi(v0.w) + bfhi(v1.w);
            }
            int node = nP0 + g8;
            int d = deg[node];
            uint4 hv = *(const uint4*)(zpb + node * DF + j8 * 8);
            float hn[8] = { bflo(hv.x), bfhi(hv.x), bflo(hv.y), bfhi(hv.y),
                            bflo(hv.z), bfhi(hv.z), bflo(hv.w), bfhi(hv.w) };
            float np = (float)(wP - d);
            float em = epsf - np;
            float dh = epsf + (float)d;
            float scv[8] = { sca.x, sca.y, sca.z, sca.w, scb.x, scb.y, scb.z, scb.w };
            float shv[8] = { sha.x, sha.y, sha.z, sha.w, shb.x, shb.y, shb.z, shb.w };
            unsigned short us[8];
            #pragma unroll
            for (int i = 0; i < 8; ++i) {
                float zf = scv[i] * (em * hn[i] + acc[i]) + dh * shv[i];
                us[i] = (unsigned short)f2bf(zf);
            }
            uint4 zpk;
            zpk.x = (unsigned)us[0] | ((unsigned)us[1] << 16);
            zpk.y = (unsigned)us[2] | ((unsigned)us[3] << 16);
            zpk.z = (unsigned)us[4] | ((unsigned)us[5] << 16);
            zpk.w = (unsigned)us[6] | ((unsigned)us[7] << 16);
            *(uint4*)&zw[(half * 8 + g8) * 80 + j8 * 8] = zpk;
        }

        // ---- GEMM1: z1 = relu(z @ W1 + b1)  (overwrites zw rows) ----
        {
            bf16x8 a0 = *(const bf16x8*)&zw[lr * 80 + lk * 8];
            bf16x8 a1 = *(const bf16x8*)&zw[lr * 80 + 32 + lk * 8];
            #pragma unroll
            for (int nt = 0; nt < 4; ++nt) {
                f32x4 acc = {0.f, 0.f, 0.f, 0.f};
                bf16x8 bb0 = *(const bf16x8*)&Wp1s[((nt * 2 + 0) * 64 + l) * 8];
                bf16x8 bb1 = *(const bf16x8*)&Wp1s[((nt * 2 + 1) * 64 + l) * 8];
                acc = __builtin_amdgcn_mfma_f32_16x16x32_bf16(a0, bb0, acc, 0, 0, 0);
                acc = __builtin_amdgcn_mfma_f32_16x16x32_bf16(a1, bb1, acc, 0, 0, 0);
                #pragma unroll
                for (int r = 0; r < 4; ++r) {
                    float v = fmaxf(acc[r] + b1f[nt], 0.0f);
                    zw[(lk * 4 + r) * 80 + nt * 16 + lr] = f2bf(v);
                }
            }
        }

        // ---- GEMM2 + epilogue (store bf16, stats on rounded value) ----
        {
            int n0 = t * 16;
            bf16x8 a0 = *(const bf16x8*)&zw[lr * 80 + lk * 8];
            bf16x8 a1 = *(const bf16x8*)&zw[lr * 80 + 32 + lk * 8];
            #pragma unroll
            for (int nt = 0; nt < 4; ++nt) {
                f32x4 acc = {0.f, 0.f, 0.f, 0.f};
                bf16x8 bb0 = *(const bf16x8*)&Wp2s[((nt * 2 + 0) * 64 + l) * 8];
                bf16x8 bb1 = *(const bf16x8*)&Wp2s[((nt * 2 + 1) * 64 + l) * 8];
                acc = __builtin_amdgcn_mfma_f32_16x16x32_bf16(a0, bb0, acc, 0, 0, 0);
                acc = __builtin_amdgcn_mfma_f32_16x16x32_bf16(a1, bb1, acc, 0, 0, 0);
                #pragma unroll
                for (int r = 0; r < 4; ++r) {
                    float v = fmaxf(fmaxf(acc[r] + b2f[nt], 0.0f) + gbf[nt], 0.0f);
                    unsigned short vb = (unsigned short)f2bf(v);
                    zout[(n0 + lk * 4 + r) * DF + nt * 16 + lr] = vb;
                    float vr = bf2f(vb);
                    ssum[nt] += vr;
                    sq[nt] += vr * vr;
                }
            }
        }
    }

    #pragma unroll
    for (int nt = 0; nt < 4; ++nt) {
        float sv = ssum[nt], qv = sq[nt];
        sv += __shfl_xor(sv, 16, 64); sv += __shfl_xor(sv, 32, 64);
        qv += __shfl_xor(qv, 16, 64); qv += __shfl_xor(qv, 32, 64);
        if (l < 16) {
            part_s[(nt * 16 + l) * NWT + t] = sv;
            part_q[(nt * 16 + l) * NWT + t] = qv;
        }
    }
}

// ---------------------------------------------------------------------------
__global__ __launch_bounds__(256) void stat_reduce_kernel(
    const float* __restrict__ part_s, const float* __restrict__ part_q,
    const float* __restrict__ gamma, const float* __restrict__ beta,
    float* __restrict__ scale, float* __restrict__ shift)
{
    __shared__ double rs[4], rq[4];
    int f = blockIdx.x, tid = threadIdx.x;
    double s = 0.0, q = 0.0;
    for (int j = tid; j < NWT; j += 256) {
        s += (double)part_s[f * NWT + j];
        q += (double)part_q[f * NWT + j];
    }
    for (int o = 32; o > 0; o >>= 1) {
        s += __shfl_down(s, o, 64);
        q += __shfl_down(q, o, 64);
    }
    if ((tid & 63) == 0) { rs[tid >> 6] = s; rq[tid >> 6] = q; }
    __syncthreads();
    if (tid == 0) {
        double st = rs[0] + rs[1] + rs[2] + rs[3];
        double qt = rq[0] + rq[1] + rq[2] + rq[3];
        double mean = st / N_NODES;
        double var = qt / N_NODES - mean * mean;
        double inv = (double)gamma[f] / sqrt(var + BN_EPS);
        scale[f] = (float)inv;
        shift[f] = (float)((double)beta[f] - mean * inv);
    }
}

// ---------------------------------------------------------------------------
__global__ __launch_bounds__(256) void pool_kernel(
    const unsigned short* __restrict__ z,
    const float* __restrict__ scale,
    const float* __restrict__ shift,
    const int* __restrict__ gstart,
    float* __restrict__ pooled,
    int layerOff)
{
    __shared__ float red[4][64];
    int g = blockIdx.x;
    int tid = threadIdx.x;
    int w = tid >> 6, f = tid & 63;

    int s = gstart[g], e = gstart[g + 1];
    float acc = 0.0f;
    for (int node = s + w; node < e; node += 4)
        acc += bf2f(z[node * DF + f]);
    red[w][f] = acc;
    __syncthreads();
    if (w == 0)
        pooled[g * LDIM + layerOff + f] =
            scale[f] * (red[0][f] + red[1][f] + red[2][f] + red[3][f])
            + (float)(e - s) * shift[f];
}

// ---------------------------------------------------------------------------
// Fused projection head, 8 rows/block: weight traffic amortized 8x.
// ---------------------------------------------------------------------------
__global__ __launch_bounds__(192) void proj_fused_kernel(
    const float* __restrict__ in,
    const float* __restrict__ Wp1, const float* __restrict__ bp1,
    const float* __restrict__ Wp2, const float* __restrict__ bp2,
    float* __restrict__ out)
{
    __shared__ float rowS[PROJ_ROWS][LDIM];
    __shared__ float hid[PROJ_ROWS][LDIM];
    int r0 = blockIdx.x * PROJ_ROWS;
    int c = threadIdx.x;
    #pragma unroll
    for (int r = 0; r < PROJ_ROWS; ++r)
        rowS[r][c] = in[(r0 + r) * LDIM + c];
    __syncthreads();

    float acc[PROJ_ROWS];
    float bv = bp1[c];
    #pragma unroll
    for (int r = 0; r < PROJ_ROWS; ++r) acc[r] = bv;
    for (int k = 0; k < LDIM; ++k) {
        float wv = Wp1[k * LDIM + c];
        #pragma unroll
        for (int r = 0; r < PROJ_ROWS; ++r) acc[r] += rowS[r][k] * wv;
    }
    #pragma unroll
    for (int r = 0; r < PROJ_ROWS; ++r) hid[r][c] = fmaxf(acc[r], 0.0f);
    __syncthreads();

    float bv2 = bp2[c];
    #pragma unroll
    for (int r = 0; r < PROJ_ROWS; ++r) acc[r] = bv2;
    for (int k = 0; k < LDIM; ++k) {
        float wv = Wp2[k * LDIM + c];
        #pragma unroll
        for (int r = 0; r < PROJ_ROWS; ++r) acc[r] += hid[r][k] * wv;
    }
    #pragma unroll
    for (int r = 0; r < PROJ_ROWS; ++r)
        out[(r0 + r) * LDIM + c] = acc[r];
}

// ---------------------------------------------------------------------------
extern "C" void kernel_launch(void* const* d_in, const int* in_sizes, int n_in,
                              void* d_out, int out_size, void* d_ws, size_t ws_size,
                              hipStream_t stream)
{
    const float* x        = (const float*)d_in[0];
    const int*   ei       = (const int*)d_in[1];
    const int*   batch    = (const int*)d_in[2];
    const float* W1       = (const float*)d_in[3];
    const float* b1       = (const float*)d_in[4];
    const float* W2       = (const float*)d_in[5];
    const float* b2       = (const float*)d_in[6];
    const float* gin_eps  = (const float*)d_in[7];
    const float* gin_bias = (const float*)d_in[8];
    const float* gamma    = (const float*)d_in[9];
    const float* beta     = (const float*)d_in[10];
    const float* Wp1      = (const float*)d_in[11];
    const float* bp1      = (const float*)d_in[12];
    const float* Wp2      = (const float*)d_in[13];
    const float* bp2      = (const float*)d_in[14];
    float* out = (float*)d_out;

    // workspace layout
    unsigned short* xb    = (unsigned short*)d_ws;          // N*64 bf16
    unsigned short* zbufA = xb + (size_t)N_NODES * DF;      // N*64 bf16
    unsigned short* zbufB = zbufA + (size_t)N_NODES * DF;   // N*64 bf16
    float* pooled = (float*)(zbufB + (size_t)N_NODES * DF); // NGRAPH*LDIM
    float* scale = pooled + (size_t)NGRAPH * LDIM;          // 64
    float* shift = scale + 64;                              // 64
    float* idsc = shift + 64;                               // 64 (1.0)
    float* idsh = idsc + 64;                                // 64 (0.0)
    float* part_s = idsh + 64;                              // 64*NWT
    float* part_q = part_s + (size_t)64 * NWT;              // 64*NWT
    int* gstart = (int*)(part_q + (size_t)64 * NWT);        // NGRAPH+1
    int* deg  = gstart + NGRAPH + 1;                        // N
    int* offT = deg + N_NODES;                              // 16*NBUCK
    int* widT = offT + 16 * NBUCK;                          // 16*NBUCK
    int* colT = widT + 16 * NBUCK;                          // COLS_CAP
    int* hist = colT + COLS_CAP;                            // NBLK*NBUCK
    int* pos  = hist + NBLK * NBUCK;                        // NBLK*NBUCK
    int* cnt  = pos + NBLK * NBUCK;                         // NBUCK
    int* bpad = cnt + NBUCK;                                // NBUCK
    int* bbase = bpad + NBUCK;                              // NBUCK
    unsigned* bucketData = (unsigned*)(bbase + NBUCK);      // NBUCK*BCAP
    short* Wpk = (short*)(bucketData + (size_t)NBUCK * BCAP); // 6*4096 bf16

    // ---- setup: x->bf16, counting-sort transposed CSR, segments, weights ----
    x2bf_kernel<<<(N_NODES * DF / 8 + 255) / 256, 256, 0, stream>>>(x, xb);
    blk_hist_kernel<<<NBLK, 256, 0, stream>>>(ei, hist);
    blk_scan_kernel<<<NBUCK, NBLK, 0, stream>>>(hist, pos, cnt);
    place_kernel<<<NBLK, 256, 0, stream>>>(ei, pos, bucketData);
    bucket_count_kernel<<<NBUCK, 256, 0, stream>>>(bucketData, cnt, deg, bpad);
    bucket_scan_kernel<<<1, 1024, 0, stream>>>(bpad, bbase);
    bucket_emit_kernel<<<NBUCK, 256, 0, stream>>>(bucketData, cnt, bbase,
                                                  colT, offT, widT);
    gstart_kernel<<<3, 256, 0, stream>>>(batch, gstart, idsc, idsh);
    pack_w_kernel<<<6, 256, 0, stream>>>(W1, W2, Wpk);

    unsigned short* zbuf[2] = {zbufA, zbufB};
    const unsigned short* zprev = xb;
    const float* sc_in = idsc;
    const float* sh_in = idsh;
    for (int l = 0; l < 3; ++l) {
        unsigned short* zcur = zbuf[l & 1];
        gin_layer_kernel<<<GIN_GRID, 512, 0, stream>>>(
            zprev, sc_in, sh_in, offT, widT, deg, colT, zcur,
            Wpk + (size_t)l * 8192,
            b1 + l * 64, b2 + l * 64, gin_eps + l, gin_bias + l * 64,
            part_s, part_q);

        stat_reduce_kernel<<<64, 256, 0, stream>>>(
            part_s, part_q, gamma + l * 64, beta + l * 64, scale, shift);

        pool_kernel<<<NGRAPH, 256, 0, stream>>>(
            zcur, scale, shift, gstart, pooled, l * 64);

        zprev = zcur;
        sc_in = scale;
        sh_in = shift;
    }

    proj_fused_kernel<<<NGRAPH / PROJ_ROWS, LDIM, 0, stream>>>(
        pooled, Wp1, bp1, Wp2, bp2, out);
}

// Round 15
// 240.610 us; speedup vs baseline: 1.1573x; 1.1036x over previous
//
#include <hip/hip_runtime.h>

#define N_NODES 100000
#define N_EDGES 800000
#define DF 64
#define NGRAPH 512
#define LDIM 192   // L * D
#define BN_EPS 1e-5
#define NTILES 6250      // N_NODES / 16
#define GIN_GRID 782     // ceil(NTILES / 8 waves)
#define NWT (GIN_GRID * 8)
#define COLS_CAP 2600000
#define NBUCK 782        // ceil(N_NODES / 128)
#define BCAP 2048
#define NBLK 128
#define CHUNK 6250       // N_EDGES / NBLK
#define REGION_CAP 6144  // per-bucket transposed region (ints)
#define PROJ_ROWS 8

typedef __attribute__((ext_vector_type(8))) short bf16x8;
typedef __attribute__((ext_vector_type(4))) float f32x4;

__device__ inline short f2bf(float x) {
    union { float f; unsigned u; } v; v.f = x;
    unsigned r = v.u + 0x7fff + ((v.u >> 16) & 1);   // RNE
    return (short)(r >> 16);
}
__device__ inline float bf2f(unsigned short u) {
    union { unsigned u; float f; } v; v.u = ((unsigned)u) << 16; return v.f;
}
__device__ inline float bflo(unsigned u) {
    union { unsigned x; float f; } v; v.x = u << 16; return v.f;
}
__device__ inline float bfhi(unsigned u) {
    union { unsigned x; float f; } v; v.x = u & 0xffff0000u; return v.f;
}

// ---------------------------------------------------------------------------
// x (fp32) -> bf16 copy
// ---------------------------------------------------------------------------
__global__ __launch_bounds__(256) void x2bf_kernel(
    const float* __restrict__ x, unsigned short* __restrict__ xb)
{
    int i = blockIdx.x * 256 + threadIdx.x;     // one per 8 elements
    const int total = N_NODES * DF / 8;
    if (i >= total) return;
    const float4* src = (const float4*)(x + (size_t)i * 8);
    float4 a = src[0], b = src[1];
    unsigned short u0 = (unsigned short)f2bf(a.x), u1 = (unsigned short)f2bf(a.y);
    unsigned short u2 = (unsigned short)f2bf(a.z), u3 = (unsigned short)f2bf(a.w);
    unsigned short u4 = (unsigned short)f2bf(b.x), u5 = (unsigned short)f2bf(b.y);
    unsigned short u6 = (unsigned short)f2bf(b.z), u7 = (unsigned short)f2bf(b.w);
    uint4 o;
    o.x = (unsigned)u0 | ((unsigned)u1 << 16);
    o.y = (unsigned)u2 | ((unsigned)u3 << 16);
    o.z = (unsigned)u4 | ((unsigned)u5 << 16);
    o.w = (unsigned)u6 | ((unsigned)u7 << 16);
    ((uint4*)xb)[i] = o;
}

// ---------------------------------------------------------------------------
// Counting-sort bucket build (no global atomics). bucket = row >> 7.
// ---------------------------------------------------------------------------
__global__ __launch_bounds__(256) void blk_hist_kernel(
    const int* __restrict__ ei, int* __restrict__ hist)
{
    __shared__ int hh[NBUCK];
    int blk = blockIdx.x, tid = threadIdx.x;
    for (int i = tid; i < NBUCK; i += 256) hh[i] = 0;
    __syncthreads();
    int start = blk * CHUNK, end = min(start + CHUNK, N_EDGES);
    for (int e = start + tid; e < end; e += 256)
        atomicAdd(&hh[ei[e] >> 7], 1);
    __syncthreads();
    for (int i = tid; i < NBUCK; i += 256) hist[blk * NBUCK + i] = hh[i];
}

__global__ __launch_bounds__(NBLK) void blk_scan_kernel(
    const int* __restrict__ hist, int* __restrict__ pos, int* __restrict__ cnt)
{
    __shared__ int buf[NBLK];
    int k = blockIdx.x, b = threadIdx.x;
    int v = hist[b * NBUCK + k];
    buf[b] = v;
    __syncthreads();
    for (int o = 1; o < NBLK; o <<= 1) {
        int t = (b >= o) ? buf[b - o] : 0;
        __syncthreads();
        buf[b] += t;
        __syncthreads();
    }
    pos[b * NBUCK + k] = buf[b] - v;
    if (b == NBLK - 1) cnt[k] = buf[b];
}

__global__ __launch_bounds__(256) void place_kernel(
    const int* __restrict__ ei, const int* __restrict__ pos,
    unsigned* __restrict__ bucketData)
{
    __shared__ int cursor[NBUCK];
    int blk = blockIdx.x, tid = threadIdx.x;
    for (int i = tid; i < NBUCK; i += 256) cursor[i] = pos[blk * NBUCK + i];
    __syncthreads();
    int start = blk * CHUNK, end = min(start + CHUNK, N_EDGES);
    for (int e = start + tid; e < end; e += 256) {
        int r = ei[e];
        int c = ei[N_EDGES + e];
        int k = r >> 7;
        int p = atomicAdd(&cursor[k], 1);   // LDS atomic, block-local
        bucketData[(size_t)k * BCAP + p] = ((unsigned)(r & 127) << 17) | (unsigned)c;
    }
}

// deg + per-bucket padded totals (pack-transposed widths: max of 8, round to 2)
__global__ __launch_bounds__(256) void bucket_count_kernel(
    const unsigned* __restrict__ bucketData, const int* __restrict__ cnt,
    int* __restrict__ deg, int* __restrict__ bpad)
{
    __shared__ int rc[128];
    __shared__ int wps[16];
    int b = blockIdx.x, tid = threadIdx.x;
    int rowbase = b << 7;
    int nrows = min(128, N_NODES - rowbase);
    int cntb = cnt[b];
    if (tid < 128) rc[tid] = 0;
    __syncthreads();
    for (int e = tid; e < cntb; e += 256)
        atomicAdd(&rc[bucketData[(size_t)b * BCAP + e] >> 17], 1);
    __syncthreads();
    if (tid < nrows) deg[rowbase + tid] = rc[tid];
    if (tid < 16) {
        int m = 0;
        #pragma unroll
        for (int i = 0; i < 8; ++i) m = max(m, rc[tid * 8 + i]);
        wps[tid] = (m + 1) & ~1;           // round up to multiple of 2
    }
    __syncthreads();
    if (tid == 0) {
        int s = 0;
        #pragma unroll
        for (int pk = 0; pk < 16; ++pk) s += 8 * wps[pk];
        bpad[b] = s;
    }
}

__global__ __launch_bounds__(1024) void bucket_scan_kernel(
    const int* __restrict__ bpad, int* __restrict__ bbase)
{
    __shared__ int buf[1024];
    int tid = threadIdx.x;
    int own = (tid < NBUCK) ? bpad[tid] : 0;
    buf[tid] = own;
    __syncthreads();
    for (int o = 1; o < 1024; o <<= 1) {
        int t = (tid >= o) ? buf[tid - o] : 0;
        __syncthreads();
        buf[tid] += t;
        __syncthreads();
    }
    if (tid < NBUCK) bbase[tid] = buf[tid] - own;
}

// Emit pack-transposed padded layout: colT[base + it*8 + g] for pack of 8 rows.
__global__ __launch_bounds__(256) void bucket_emit_kernel(
    const unsigned* __restrict__ bucketData, const int* __restrict__ cnt,
    const int* __restrict__ bbase,
    int* __restrict__ colT, int* __restrict__ offT, int* __restrict__ widT)
{
    __shared__ int rc[128], rcur[128];
    __shared__ int wps[16], pstart[16];
    __shared__ int region[REGION_CAP];
    __shared__ int totalS;
    int b = blockIdx.x, tid = threadIdx.x;
    int rowbase = b << 7;
    int nrows = min(128, N_NODES - rowbase);
    int cntb = cnt[b];
    int base = bbase[b];
    if (tid < 128) { rc[tid] = 0; rcur[tid] = 0; }
    __syncthreads();
    for (int e = tid; e < cntb; e += 256)
        atomicAdd(&rc[bucketData[(size_t)b * BCAP + e] >> 17], 1);
    __syncthreads();
    if (tid < 16) {
        int m = 0;
        #pragma unroll
        for (int i = 0; i < 8; ++i) m = max(m, rc[tid * 8 + i]);
        wps[tid] = (m + 1) & ~1;
    }
    __syncthreads();
    if (tid == 0) {
        int run = 0;
        #pragma unroll
        for (int pk = 0; pk < 16; ++pk) { pstart[pk] = run; run += 8 * wps[pk]; }
        totalS = run;
    }
    __syncthreads();
    int total = totalS;
    // real edges -> transposed slots
    for (int e = tid; e < cntb; e += 256) {
        unsigned p = bucketData[(size_t)b * BCAP + e];
        int lr = p >> 17;
        int c = p & 0x1FFFF;
        int slot = atomicAdd(&rcur[lr], 1);
        int pk = lr >> 3, g = lr & 7;
        region[pstart[pk] + slot * 8 + g] = c * DF;
    }
    __syncthreads();
    // pads point at the node's own row (corrected algebraically in gather)
    for (int i = tid; i < nrows; i += 256) {
        int pk = i >> 3, g = i & 7;
        int wp = wps[pk];
        int sent = (rowbase + i) * DF;
        for (int slot = rc[i]; slot < wp; ++slot)
            region[pstart[pk] + slot * 8 + g] = sent;
    }
    __syncthreads();
    for (int k = tid; k < total; k += 256) colT[base + k] = region[k];
    if (tid < 16 && tid * 8 < nrows) {
        offT[b * 16 + tid] = base + pstart[tid];
        widT[b * 16 + tid] = wps[tid];
    }
}

// ---------------------------------------------------------------------------
__global__ __launch_bounds__(256) void gstart_kernel(
    const int* __restrict__ batch, int* __restrict__ gstart,
    float* __restrict__ idsc, float* __restrict__ idsh)
{
    int g = blockIdx.x * 256 + threadIdx.x;
    if (g < 64) { idsc[g] = 1.0f; idsh[g] = 0.0f; }
    if (g > NGRAPH) return;
    if (g == NGRAPH) { gstart[g] = N_NODES; return; }
    int lo = 0, hi = N_NODES;
    while (lo < hi) {
        int mid = (lo + hi) >> 1;
        if (batch[mid] < g) lo = mid + 1; else hi = mid;
    }
    gstart[g] = lo;
}

// ---------------------------------------------------------------------------
__global__ __launch_bounds__(256) void pack_w_kernel(
    const float* __restrict__ W1, const float* __restrict__ W2,
    short* __restrict__ Wpk)
{
    int u = blockIdx.x;            // 0..5 = layer*2 + gemm
    int layer = u >> 1, gm = u & 1;
    const float* W = (gm ? W2 : W1) + layer * 4096;
    short* dst = Wpk + u * 4096;
    for (int idx = threadIdx.x; idx < 4096; idx += 256) {
        int i = idx & 7;
        int l = (idx >> 3) & 63;
        int rest = idx >> 9;       // nt*2+kt
        int kt = rest & 1, nt = rest >> 1;
        int k = kt * 32 + (l >> 4) * 8 + i;
        int n = nt * 16 + (l & 15);
        dst[idx] = f2bf(W[k * 64 + n]);
    }
}

// ---------------------------------------------------------------------------
// Fused GIN layer (MFMA) + per-graph pooling. 8 waves/block, one 16-node
// tile (2 packs) per wave. Gather: 8 rows per wave-load, 2-deep pipelined.
// Pool: raw z3 sums accumulated into pooled[] (atomic per column per tile
// for single-graph tiles; per-element for boundary tiles). BN applied later.
// ---------------------------------------------------------------------------
__global__ __launch_bounds__(512) void gin_layer_kernel(
    const unsigned short* __restrict__ zpb,  // bf16 activations (xb for l=0)
    const float* __restrict__ sc_in,
    const float* __restrict__ sh_in,
    const int* __restrict__ offT,
    const int* __restrict__ widT,
    const int* __restrict__ deg,
    const int* __restrict__ colT,
    const int* __restrict__ batch,
    unsigned short* __restrict__ zout,       // bf16
    float* __restrict__ pooled,              // raw per-graph sums
    int lOff,
    const short* __restrict__ Wpk,
    const float* __restrict__ b1,
    const float* __restrict__ b2,
    const float* __restrict__ gin_eps,
    const float* __restrict__ gin_bias,
    float* __restrict__ part_s,
    float* __restrict__ part_q)
{
    __shared__ __align__(16) short Wp1s[4096];
    __shared__ __align__(16) short Wp2s[4096];
    __shared__ __align__(16) short zs[8][16 * 80];   // stride 80 shorts/row

    int tid = threadIdx.x;
    {   // stage packed weights (16 KB), once per block
        const short4* s1 = (const short4*)Wpk;
        const short4* s2 = (const short4*)(Wpk + 4096);
        short4* d1 = (short4*)Wp1s;
        short4* d2 = (short4*)Wp2s;
        for (int i = tid; i < 1024; i += 512) { d1[i] = s1[i]; d2[i] = s2[i]; }
    }

    int w = tid >> 6, l = tid & 63;
    int lr = l & 15;       // MFMA indices
    int lk = l >> 4;
    int g8 = l >> 3;       // gather group (node within pack)
    int j8 = l & 7;        // feature slot (features 8*j8 .. 8*j8+7)
    float epsf = 1.0f + gin_eps[0];
    float b1f[4], b2f[4], gbf[4];
    #pragma unroll
    for (int nt = 0; nt < 4; ++nt) {
        b1f[nt] = b1[nt * 16 + lr];
        b2f[nt] = b2[nt * 16 + lr];
        gbf[nt] = gin_bias[nt * 16 + lr];
    }
    float4 sca = *(const float4*)&sc_in[j8 * 8];
    float4 scb = *(const float4*)&sc_in[j8 * 8 + 4];
    float4 sha = *(const float4*)&sh_in[j8 * 8];
    float4 shb = *(const float4*)&sh_in[j8 * 8 + 4];
    float ssum[4] = {0, 0, 0, 0}, sq[4] = {0, 0, 0, 0};
    short* zw = zs[w];
    __syncthreads();

    int t = blockIdx.x * 8 + w;
    bool active = t < NTILES;
    int n0 = t * 16;
    int g0 = 0;
    bool uni = true;
    int gr[4];

    if (active) {
        // graph-uniformity of this tile (wave-uniform result)
        g0 = batch[n0];
        int gl = batch[n0 + (l & 15)];
        uni = __all(gl == g0);
        if (!uni) {
            #pragma unroll
            for (int r = 0; r < 4; ++r) gr[r] = batch[n0 + lk * 4 + r];
        }

        // ---- gather: two packs of 8 nodes, 2-deep pipelined ----
        #pragma unroll
        for (int half = 0; half < 2; ++half) {
            int p = t * 2 + half;
            int nP0 = p * 8;
            int sP = __builtin_amdgcn_readfirstlane(offT[p]);
            int wP = __builtin_amdgcn_readfirstlane(widT[p]);
            float acc[8];
            #pragma unroll
            for (int i = 0; i < 8; ++i) acc[i] = 0.0f;
            if (wP > 0) {
                int co0 = colT[sP + g8];
                int co1 = colT[sP + 8 + g8];
                uint4 v0 = *(const uint4*)(zpb + co0 + j8 * 8);
                uint4 v1 = *(const uint4*)(zpb + co1 + j8 * 8);
                #pragma unroll 1
                for (int it = 2; it < wP; it += 2) {
                    int cn0 = colT[sP + it * 8 + g8];
                    int cn1 = colT[sP + it * 8 + 8 + g8];
                    uint4 nv0 = *(const uint4*)(zpb + cn0 + j8 * 8);
                    uint4 nv1 = *(const uint4*)(zpb + cn1 + j8 * 8);
                    acc[0] += bflo(v0.x) + bflo(v1.x);
                    acc[1] += bfhi(v0.x) + bfhi(v1.x);
                    acc[2] += bflo(v0.y) + bflo(v1.y);
                    acc[3] += bfhi(v0.y) + bfhi(v1.y);
                    acc[4] += bflo(v0.z) + bflo(v1.z);
                    acc[5] += bfhi(v0.z) + bfhi(v1.z);
                    acc[6] += bflo(v0.w) + bflo(v1.w);
                    acc[7] += bfhi(v0.w) + bfhi(v1.w);
                    v0 = nv0; v1 = nv1;
                }
                acc[0] += bflo(v0.x) + bflo(v1.x);
                acc[1] += bfhi(v0.x) + bfhi(v1.x);
                acc[2] += bflo(v0.y) + bflo(v1.y);
                acc[3] += bfhi(v0.y) + bfhi(v1.y);
                acc[4] += bflo(v0.z) + bflo(v1.z);
                acc[5] += bfhi(v0.z) + bfhi(v1.z);
                acc[6] += bflo(v0.w) + bflo(v1.w);
                acc[7] += bfhi(v0.w) + bfhi(v1.w);
            }
            int node = nP0 + g8;
            int d = deg[node];
            uint4 hv = *(const uint4*)(zpb + node * DF + j8 * 8);
            float hn[8] = { bflo(hv.x), bfhi(hv.x), bflo(hv.y), bfhi(hv.y),
                            bflo(hv.z), bfhi(hv.z), bflo(hv.w), bfhi(hv.w) };
            float np = (float)(wP - d);
            float em = epsf - np;
            float dh = epsf + (float)d;
            float scv[8] = { sca.x, sca.y, sca.z, sca.w, scb.x, scb.y, scb.z, scb.w };
            float shv[8] = { sha.x, sha.y, sha.z, sha.w, shb.x, shb.y, shb.z, shb.w };
            unsigned short us[8];
            #pragma unroll
            for (int i = 0; i < 8; ++i) {
                float zf = scv[i] * (em * hn[i] + acc[i]) + dh * shv[i];
                us[i] = (unsigned short)f2bf(zf);
            }
            uint4 zpk;
            zpk.x = (unsigned)us[0] | ((unsigned)us[1] << 16);
            zpk.y = (unsigned)us[2] | ((unsigned)us[3] << 16);
            zpk.z = (unsigned)us[4] | ((unsigned)us[5] << 16);
            zpk.w = (unsigned)us[6] | ((unsigned)us[7] << 16);
            *(uint4*)&zw[(half * 8 + g8) * 80 + j8 * 8] = zpk;
        }

        // ---- GEMM1: z1 = relu(z @ W1 + b1)  (overwrites zw rows) ----
        {
            bf16x8 a0 = *(const bf16x8*)&zw[lr * 80 + lk * 8];
            bf16x8 a1 = *(const bf16x8*)&zw[lr * 80 + 32 + lk * 8];
            #pragma unroll
            for (int nt = 0; nt < 4; ++nt) {
                f32x4 acc = {0.f, 0.f, 0.f, 0.f};
                bf16x8 bb0 = *(const bf16x8*)&Wp1s[((nt * 2 + 0) * 64 + l) * 8];
                bf16x8 bb1 = *(const bf16x8*)&Wp1s[((nt * 2 + 1) * 64 + l) * 8];
                acc = __builtin_amdgcn_mfma_f32_16x16x32_bf16(a0, bb0, acc, 0, 0, 0);
                acc = __builtin_amdgcn_mfma_f32_16x16x32_bf16(a1, bb1, acc, 0, 0, 0);
                #pragma unroll
                for (int r = 0; r < 4; ++r) {
                    float v = fmaxf(acc[r] + b1f[nt], 0.0f);
                    zw[(lk * 4 + r) * 80 + nt * 16 + lr] = f2bf(v);
                }
            }
        }

        // ---- GEMM2 + epilogue (store bf16, stats + boundary pooling) ----
        {
            bf16x8 a0 = *(const bf16x8*)&zw[lr * 80 + lk * 8];
            bf16x8 a1 = *(const bf16x8*)&zw[lr * 80 + 32 + lk * 8];
            #pragma unroll
            for (int nt = 0; nt < 4; ++nt) {
                f32x4 acc = {0.f, 0.f, 0.f, 0.f};
                bf16x8 bb0 = *(const bf16x8*)&Wp2s[((nt * 2 + 0) * 64 + l) * 8];
                bf16x8 bb1 = *(const bf16x8*)&Wp2s[((nt * 2 + 1) * 64 + l) * 8];
                acc = __builtin_amdgcn_mfma_f32_16x16x32_bf16(a0, bb0, acc, 0, 0, 0);
                acc = __builtin_amdgcn_mfma_f32_16x16x32_bf16(a1, bb1, acc, 0, 0, 0);
                #pragma unroll
                for (int r = 0; r < 4; ++r) {
                    float v = fmaxf(fmaxf(acc[r] + b2f[nt], 0.0f) + gbf[nt], 0.0f);
                    unsigned short vb = (unsigned short)f2bf(v);
                    zout[(n0 + lk * 4 + r) * DF + nt * 16 + lr] = vb;
                    float vr = bf2f(vb);
                    ssum[nt] += vr;
                    sq[nt] += vr * vr;
                    if (!uni)
                        unsafeAtomicAdd(&pooled[gr[r] * LDIM + lOff + nt * 16 + lr], vr);
                }
            }
        }
    }

    // ---- BN partials + single-graph-tile pooling ----
    float svv[4];
    #pragma unroll
    for (int nt = 0; nt < 4; ++nt) {
        float sv = ssum[nt], qv = sq[nt];
        sv += __shfl_xor(sv, 16, 64); sv += __shfl_xor(sv, 32, 64);
        qv += __shfl_xor(qv, 16, 64); qv += __shfl_xor(qv, 32, 64);
        svv[nt] = sv;
        if (l < 16) {
            part_s[(nt * 16 + l) * NWT + t] = sv;
            part_q[(nt * 16 + l) * NWT + t] = qv;
        }
    }
    if (active && uni && l < 16) {
        #pragma unroll
        for (int nt = 0; nt < 4; ++nt)
            unsafeAtomicAdd(&pooled[g0 * LDIM + lOff + nt * 16 + l], svv[nt]);
    }
}

// ---------------------------------------------------------------------------
__global__ __launch_bounds__(256) void stat_reduce_kernel(
    const float* __restrict__ part_s, const float* __restrict__ part_q,
    const float* __restrict__ gamma, const float* __restrict__ beta,
    float* __restrict__ scale, float* __restrict__ shift)
{
    __shared__ double rs[4], rq[4];
    int f = blockIdx.x, tid = threadIdx.x;
    double s = 0.0, q = 0.0;
    for (int j = tid; j < NWT; j += 256) {
        s += (double)part_s[f * NWT + j];
        q += (double)part_q[f * NWT + j];
    }
    for (int o = 32; o > 0; o >>= 1) {
        s += __shfl_down(s, o, 64);
        q += __shfl_down(q, o, 64);
    }
    if ((tid & 63) == 0) { rs[tid >> 6] = s; rq[tid >> 6] = q; }
    __syncthreads();
    if (tid == 0) {
        double st = rs[0] + rs[1] + rs[2] + rs[3];
        double qt = rq[0] + rq[1] + rq[2] + rq[3];
        double mean = st / N_NODES;
        double var = qt / N_NODES - mean * mean;
        double inv = (double)gamma[f] / sqrt(var + BN_EPS);
        scale[f] = (float)inv;
        shift[f] = (float)((double)beta[f] - mean * inv);
    }
}

// ---------------------------------------------------------------------------
// Fused projection head, 8 rows/block. Applies BN to raw pooled sums on load:
// pooled_final = scale3[c]*raw + cnt(g)*shift3[c]
// ---------------------------------------------------------------------------
__global__ __launch_bounds__(192) void proj_fused_kernel(
    const float* __restrict__ praw,
    const float* __restrict__ scale3, const float* __restrict__ shift3,
    const int* __restrict__ gstart,
    const float* __restrict__ Wp1, const float* __restrict__ bp1,
    const float* __restrict__ Wp2, const float* __restrict__ bp2,
    float* __restrict__ out)
{
    __shared__ float rowS[PROJ_ROWS][LDIM];
    __shared__ float hid[PROJ_ROWS][LDIM];
    int r0 = blockIdx.x * PROJ_ROWS;
    int c = threadIdx.x;
    float scc = scale3[c], shc = shift3[c];
    #pragma unroll
    for (int r = 0; r < PROJ_ROWS; ++r) {
        int g = r0 + r;
        float cntg = (float)(gstart[g + 1] - gstart[g]);
        rowS[r][c] = scc * praw[g * LDIM + c] + cntg * shc;
    }
    __syncthreads();

    float acc[PROJ_ROWS];
    float bv = bp1[c];
    #pragma unroll
    for (int r = 0; r < PROJ_ROWS; ++r) acc[r] = bv;
    for (int k = 0; k < LDIM; ++k) {
        float wv = Wp1[k * LDIM + c];
        #pragma unroll
        for (int r = 0; r < PROJ_ROWS; ++r) acc[r] += rowS[r][k] * wv;
    }
    #pragma unroll
    for (int r = 0; r < PROJ_ROWS; ++r) hid[r][c] = fmaxf(acc[r], 0.0f);
    __syncthreads();

    float bv2 = bp2[c];
    #pragma unroll
    for (int r = 0; r < PROJ_ROWS; ++r) acc[r] = bv2;
    for (int k = 0; k < LDIM; ++k) {
        float wv = Wp2[k * LDIM + c];
        #pragma unroll
        for (int r = 0; r < PROJ_ROWS; ++r) acc[r] += hid[r][k] * wv;
    }
    #pragma unroll
    for (int r = 0; r < PROJ_ROWS; ++r)
        out[(r0 + r) * LDIM + c] = acc[r];
}

// ---------------------------------------------------------------------------
extern "C" void kernel_launch(void* const* d_in, const int* in_sizes, int n_in,
                              void* d_out, int out_size, void* d_ws, size_t ws_size,
                              hipStream_t stream)
{
    const float* x        = (const float*)d_in[0];
    const int*   ei       = (const int*)d_in[1];
    const int*   batch    = (const int*)d_in[2];
    const float* W1       = (const float*)d_in[3];
    const float* b1       = (const float*)d_in[4];
    const float* W2       = (const float*)d_in[5];
    const float* b2       = (const float*)d_in[6];
    const float* gin_eps  = (const float*)d_in[7];
    const float* gin_bias = (const float*)d_in[8];
    const float* gamma    = (const float*)d_in[9];
    const float* beta     = (const float*)d_in[10];
    const float* Wp1      = (const float*)d_in[11];
    const float* bp1      = (const float*)d_in[12];
    const float* Wp2      = (const float*)d_in[13];
    const float* bp2      = (const float*)d_in[14];
    float* out = (float*)d_out;

    // workspace layout
    unsigned short* xb    = (unsigned short*)d_ws;          // N*64 bf16
    unsigned short* zbufA = xb + (size_t)N_NODES * DF;      // N*64 bf16
    unsigned short* zbufB = zbufA + (size_t)N_NODES * DF;   // N*64 bf16
    float* pooled = (float*)(zbufB + (size_t)N_NODES * DF); // NGRAPH*LDIM (raw)
    float* scale3 = pooled + (size_t)NGRAPH * LDIM;         // 192
    float* shift3 = scale3 + LDIM;                          // 192
    float* idsc = shift3 + LDIM;                            // 64 (1.0)
    float* idsh = idsc + 64;                                // 64 (0.0)
    float* part_s = idsh + 64;                              // 64*NWT
    float* part_q = part_s + (size_t)64 * NWT;              // 64*NWT
    int* gstart = (int*)(part_q + (size_t)64 * NWT);        // NGRAPH+1
    int* deg  = gstart + NGRAPH + 1;                        // N
    int* offT = deg + N_NODES;                              // 16*NBUCK
    int* widT = offT + 16 * NBUCK;                          // 16*NBUCK
    int* colT = widT + 16 * NBUCK;                          // COLS_CAP
    int* hist = colT + COLS_CAP;                            // NBLK*NBUCK
    int* pos  = hist + NBLK * NBUCK;                        // NBLK*NBUCK
    int* cnt  = pos + NBLK * NBUCK;                         // NBUCK
    int* bpad = cnt + NBUCK;                                // NBUCK
    int* bbase = bpad + NBUCK;                              // NBUCK
    unsigned* bucketData = (unsigned*)(bbase + NBUCK);      // NBUCK*BCAP
    short* Wpk = (short*)(bucketData + (size_t)NBUCK * BCAP); // 6*4096 bf16

    // ---- setup: x->bf16, counting-sort transposed CSR, segments, weights ----
    hipMemsetAsync(pooled, 0, (size_t)NGRAPH * LDIM * sizeof(float), stream);
    x2bf_kernel<<<(N_NODES * DF / 8 + 255) / 256, 256, 0, stream>>>(x, xb);
    blk_hist_kernel<<<NBLK, 256, 0, stream>>>(ei, hist);
    blk_scan_kernel<<<NBUCK, NBLK, 0, stream>>>(hist, pos, cnt);
    place_kernel<<<NBLK, 256, 0, stream>>>(ei, pos, bucketData);
    bucket_count_kernel<<<NBUCK, 256, 0, stream>>>(bucketData, cnt, deg, bpad);
    bucket_scan_kernel<<<1, 1024, 0, stream>>>(bpad, bbase);
    bucket_emit_kernel<<<NBUCK, 256, 0, stream>>>(bucketData, cnt, bbase,
                                                  colT, offT, widT);
    gstart_kernel<<<3, 256, 0, stream>>>(batch, gstart, idsc, idsh);
    pack_w_kernel<<<6, 256, 0, stream>>>(W1, W2, Wpk);

    unsigned short* zbuf[2] = {zbufA, zbufB};
    const unsigned short* zprev = xb;
    const float* sc_in = idsc;
    const float* sh_in = idsh;
    for (int l = 0; l < 3; ++l) {
        unsigned short* zcur = zbuf[l & 1];
        gin_layer_kernel<<<GIN_GRID, 512, 0, stream>>>(
            zprev, sc_in, sh_in, offT, widT, deg, colT, batch, zcur,
            pooled, l * 64,
            Wpk + (size_t)l * 8192,
            b1 + l * 64, b2 + l * 64, gin_eps + l, gin_bias + l * 64,
            part_s, part_q);

        stat_reduce_kernel<<<64, 256, 0, stream>>>(
            part_s, part_q, gamma + l * 64, beta + l * 64,
            scale3 + l * 64, shift3 + l * 64);

        zprev = zcur;
        sc_in = scale3 + l * 64;
        sh_in = shift3 + l * 64;
    }

    proj_fused_kernel<<<NGRAPH / PROJ_ROWS, LDIM, 0, stream>>>(
        pooled, scale3, shift3, gstart, Wp1, bp1, Wp2, bp2, out);
}